// Round 6
// baseline (852.634 us; speedup 1.0000x reference)
//
#include <hip/hip_runtime.h>

#define B_ 8
#define P_ 512
#define Q_ 64
#define A_ 16
#define H_ 128
#define H2_ 256
#define H10_ 1280
#define G_ 384

typedef float f32x4 __attribute__((ext_vector_type(4)));
typedef _Float16 half4_t __attribute__((ext_vector_type(4)));
typedef _Float16 half2_t __attribute__((ext_vector_type(2)));

// division-free transcendentals (v_exp_f32 is exp2; v_rcp_f32 ~1e-7 rel err)
__device__ __forceinline__ float fast_tanh(float x) {
  return 1.f - 2.f * __builtin_amdgcn_rcpf(1.f + __builtin_amdgcn_exp2f(2.88539008f * x));
}
__device__ __forceinline__ float fast_sigm(float x) {
  return __builtin_amdgcn_rcpf(1.f + __builtin_amdgcn_exp2f(-1.44269504f * x));
}

// raw barrier: LDS drain only — vmcnt (global prefetch/stores) stays in flight
#define GRUBAR() asm volatile("s_waitcnt lgkmcnt(0)\n\ts_barrier" ::: "memory")

// ================= fused preprocessing mega-kernel =================
// blockIdx ranges:
//  [0,24)        alters pooling
//  [24,152)      prep_frag Wd        (32768 elems)
//  [152,2072)    prep_frag gWih_f    (491520)
//  [2072,3992)   prep_frag gWih_b
//  [3992,4184)   prep_frag gWhh_f    (49152)  -> MFMA B-frag layout
//  [4184,4376)   prep_frag gWhh_b
//  [4376,4888)   gemm4 pas@Wc1 -> p1
//  [4888,4952)   gemm4 qry@Wc2 -> q1
//  [4952,5464)   gemm4 pas@Wm  -> pmp
//  [5464,5528)   gemm4 qry@Wm  -> pmq
//  [5528,6552)   gemm4 pas@Wb  -> pasWb
//  [6552,6808)   qscore (2 rows/block)
#define NB_PRE 6808

__device__ __forceinline__ void prep_frag_body(int idx, const float* __restrict__ W,
                                               _Float16* __restrict__ out, int KT, int HT, int N) {
  int total = KT * HT * 64 * 4;
  if (idx >= total) return;
  int e = idx & 3;
  int l = (idx >> 2) & 63;
  int rest = idx >> 8;
  int ht = rest % HT;
  int ks = rest / HT;
  int k = ks * 16 + ((l >> 4) << 2) + e;
  int n = ht * 16 + (l & 15);
  out[idx] = (_Float16)W[(size_t)k * N + n];
}

__device__ __forceinline__ void gemm4_body(int id, const float* __restrict__ A,
                                           const float* __restrict__ W, float* __restrict__ C,
                                           int M, int K, int N) {
  int total = (M >> 2) * N;
  if (id >= total) return;
  int n = id % N;
  int m0 = (id / N) << 2;
  const float* a0 = A + (size_t)m0 * K;
  const float* a1 = a0 + K;
  const float* a2 = a1 + K;
  const float* a3 = a2 + K;
  float c0 = 0.f, c1 = 0.f, c2 = 0.f, c3 = 0.f;
#pragma unroll 4
  for (int k = 0; k < K; ++k) {
    float wv = W[(size_t)k * N + n];
    c0 += a0[k] * wv; c1 += a1[k] * wv; c2 += a2[k] * wv; c3 += a3[k] * wv;
  }
  C[(size_t)m0 * N + n] = c0;
  C[(size_t)(m0 + 1) * N + n] = c1;
  C[(size_t)(m0 + 2) * N + n] = c2;
  C[(size_t)(m0 + 3) * N + n] = c3;
}

__global__ __launch_bounds__(256) void k_pre(
    const float* __restrict__ a1, const float* __restrict__ a2, const float* __restrict__ a3,
    const int* __restrict__ m1, const int* __restrict__ m2, const int* __restrict__ m3,
    const float* __restrict__ a_att_w, float* __restrict__ alters,
    const float* __restrict__ Wd, _Float16* __restrict__ wd_sw,
    const float* __restrict__ gWih_f, const float* __restrict__ gWih_b,
    _Float16* __restrict__ gih_sw,
    const float* __restrict__ gWhh_f, const float* __restrict__ gWhh_b,
    _Float16* __restrict__ whh_sw,
    const float* __restrict__ pas, const float* __restrict__ qry,
    const float* __restrict__ Wc1, float* __restrict__ p1,
    const float* __restrict__ Wc2, float* __restrict__ q1,
    const float* __restrict__ Wm, float* __restrict__ pmp, float* __restrict__ pmq,
    const float* __restrict__ Wb, float* __restrict__ pasWb,
    const float* __restrict__ wq, const float* __restrict__ vq, float* __restrict__ sjraw) {
  int bx = blockIdx.x;
  int tid = threadIdx.x;
  if (bx < 24) {
    // ---- alt pooling ----
    int b = bx / 3, i = bx % 3;
    const float* x = (i == 0) ? a1 : (i == 1) ? a2 : a3;
    const int* mk = (i == 0) ? m1 : (i == 1) ? m2 : m3;
    __shared__ float sc[A_];
    __shared__ float sw[A_];
    if (tid < A_) {
      const float* row = x + ((size_t)(b * A_ + tid)) * H_;
      float acc = 0.f;
      for (int h = 0; h < H_; ++h) acc += row[h] * a_att_w[h];
      sc[tid] = (mk[b * A_ + tid] != 0) ? acc : -1e30f;
    }
    __syncthreads();
    if (tid == 0) {
      float mx = -1e30f;
      for (int a = 0; a < A_; ++a) mx = fmaxf(mx, sc[a]);
      float s = 0.f;
      for (int a = 0; a < A_; ++a) { float e = __expf(sc[a] - mx); sw[a] = e; s += e; }
      float inv = 1.f / s;
      for (int a = 0; a < A_; ++a) sw[a] *= inv;
    }
    __syncthreads();
    if (tid < H_) {
      float acc = 0.f;
      for (int a = 0; a < A_; ++a) acc += sw[a] * x[((size_t)(b * A_ + a)) * H_ + tid];
      alters[((size_t)(b * 3 + i)) * H_ + tid] = acc;
    }
    return;
  }
  bx -= 24;
  if (bx < 128) { prep_frag_body(bx * 256 + tid, Wd, wd_sw, 16, 8, H_); return; }
  bx -= 128;
  if (bx < 1920) { prep_frag_body(bx * 256 + tid, gWih_f, gih_sw, 80, 24, G_); return; }
  bx -= 1920;
  if (bx < 1920) {
    prep_frag_body(bx * 256 + tid, gWih_b, gih_sw + (size_t)80 * 24 * 64 * 4, 80, 24, G_);
    return;
  }
  bx -= 1920;
  if (bx < 192) { prep_frag_body(bx * 256 + tid, gWhh_f, whh_sw, 8, 24, G_); return; }
  bx -= 192;
  if (bx < 192) {
    prep_frag_body(bx * 256 + tid, gWhh_b, whh_sw + (size_t)8 * 24 * 64 * 4, 8, 24, G_);
    return;
  }
  bx -= 192;
  if (bx < 512) { gemm4_body(bx * 256 + tid, pas, Wc1, p1, B_ * P_, H2_, H_); return; }
  bx -= 512;
  if (bx < 64) { gemm4_body(bx * 256 + tid, qry, Wc2, q1, B_ * Q_, H2_, H_); return; }
  bx -= 64;
  if (bx < 512) { gemm4_body(bx * 256 + tid, pas, Wm, pmp, B_ * P_, H2_, H_); return; }
  bx -= 512;
  if (bx < 64) { gemm4_body(bx * 256 + tid, qry, Wm, pmq, B_ * Q_, H2_, H_); return; }
  bx -= 64;
  if (bx < 1024) { gemm4_body(bx * 256 + tid, pas, Wb, pasWb, B_ * P_, H2_, H2_); return; }
  bx -= 1024;
  {
    // ---- qscore: 2 rows per block ----
    int rs = tid >> 7;            // row within block
    int h = tid & 127;
    int row = bx * 2 + rs;
    const float* qr = qry + (size_t)row * H2_;
    float acc = 0.f;
#pragma unroll 4
    for (int d = 0; d < H2_; ++d) acc += qr[d] * wq[(size_t)d * H_ + h];
    float v = fast_tanh(acc) * vq[h];
    for (int m = 32; m >= 1; m >>= 1) v += __shfl_xor(v, m);
    __shared__ float par[2][2];
    if ((h & 63) == 0) par[rs][h >> 6] = v;
    __syncthreads();
    if (h == 0) sjraw[row] = par[rs][0] + par[rs][1];
  }
}

// ================= sc_d scores (MFMA) + rq fused launch =================
__global__ __launch_bounds__(256) void k_scd_rq(
    const float* __restrict__ pas, const float* __restrict__ qry,
    const _Float16* __restrict__ wd_sw, const float* __restrict__ vd,
    float* __restrict__ scd,
    const float* __restrict__ sjraw, const int* __restrict__ qmask,
    const float* __restrict__ wp2, float* __restrict__ rqw2) {
  int bx0 = blockIdx.x;
  int tid = threadIdx.x;
  if (bx0 < B_ * Q_ * 8) {
    int pt = bx0 & 7;
    int rem = bx0 >> 3;
    int q = rem & (Q_ - 1);
    int b = rem >> 6;
    int w = tid >> 6, l = tid & 63;
    __shared__ __align__(16) float qs[H2_];
    __shared__ float vds[H_];
    if (tid < H2_) qs[tid] = qry[((size_t)(b * Q_ + q)) * H2_ + tid];
    if (tid < H_) vds[tid] = vd[tid];
    __syncthreads();
    int arow = pt * 64 + w * 16 + (l & 15);
    const float* prow = pas + ((size_t)(b * P_) + arow) * H2_;
    int ko = (l >> 4) << 2;
    f32x4 acc[8] = {};
#pragma unroll
    for (int ks = 0; ks < 16; ++ks) {
      int j0 = ks * 16 + ko;
      float4 pa = *(const float4*)(prow + j0);
      float4 qa = *(const float4*)(qs + j0);
      half4_t a;
      a[0] = (_Float16)(pa.x * qa.x);
      a[1] = (_Float16)(pa.y * qa.y);
      a[2] = (_Float16)(pa.z * qa.z);
      a[3] = (_Float16)(pa.w * qa.w);
      const _Float16* bb = wd_sw + (((size_t)(ks * 8) * 64) + l) * 4;
#pragma unroll
      for (int ht = 0; ht < 8; ++ht) {
        half4_t bf = *(const half4_t*)(bb + (size_t)ht * 64 * 4);
        acc[ht] = __builtin_amdgcn_mfma_f32_16x16x16f16(a, bf, acc[ht], 0, 0, 0);
      }
    }
    float part[4] = {0.f, 0.f, 0.f, 0.f};
#pragma unroll
    for (int ht = 0; ht < 8; ++ht) {
      float v = vds[ht * 16 + (l & 15)];
#pragma unroll
      for (int j = 0; j < 4; ++j) part[j] += v * fast_tanh(acc[ht][j]);
    }
#pragma unroll
    for (int j = 0; j < 4; ++j) {
      float s = part[j];
      s += __shfl_xor(s, 1);
      s += __shfl_xor(s, 2);
      s += __shfl_xor(s, 4);
      s += __shfl_xor(s, 8);
      part[j] = s;
    }
    if ((l & 15) == 0) {
      int pr = pt * 64 + w * 16 + ((l >> 4) << 2);
#pragma unroll
      for (int j = 0; j < 4; ++j)
        scd[((size_t)b * P_ + pr + j) * Q_ + q] = part[j];
    }
    return;
  }
  {
    // ---- rq + rq@wp2 ----
    int b = bx0 - B_ * Q_ * 8;
    int t = tid;
    __shared__ float sj[Q_];
    __shared__ float rql[H2_];
    if (t < Q_) {
      float s = (qmask[b * Q_ + t] != 0) ? sjraw[b * Q_ + t] : -1e30f;
      float mx = s;
      for (int m = 32; m >= 1; m >>= 1) mx = fmaxf(mx, __shfl_xor(mx, m));
      float e = __expf(s - mx);
      float sum = e;
      for (int m = 32; m >= 1; m >>= 1) sum += __shfl_xor(sum, m);
      sj[t] = e / sum;
    }
    __syncthreads();
    {
      float acc = 0.f;
      const float* qcol = qry + (size_t)b * Q_ * H2_ + t;
#pragma unroll 8
      for (int q = 0; q < Q_; ++q) acc += sj[q] * qcol[(size_t)q * H2_];
      rql[t] = acc;
    }
    __syncthreads();
    if (t < H_) {
      float acc = 0.f;
#pragma unroll 4
      for (int d = 0; d < H2_; ++d) acc += rql[d] * wp2[(size_t)d * H_ + t];
      rqw2[b * H_ + t] = acc;
    }
  }
}

// ---------------- fused per-(b,p): sc_c/sc_b/sc_m scores + 4 masked softmaxes + attends ----------------
__global__ __launch_bounds__(256) void k_attend(
    const float* __restrict__ pas, const float* __restrict__ qry,
    const float* __restrict__ p1, const float* __restrict__ q1,
    const float* __restrict__ pmp, const float* __restrict__ pmq,
    const float* __restrict__ pasWb, const float* __restrict__ scd,
    const float* __restrict__ vc, const float* __restrict__ vm,
    const int* __restrict__ qmask, _Float16* __restrict__ agg_h) {
  int bx = blockIdx.x;
  int b = bx >> 9, p = bx & (P_ - 1);
  int tid = threadIdx.x;
  __shared__ float p1s[H_], pmps[H_];
  __shared__ float pbs[H2_];
  __shared__ float ssc[4][Q_];
  __shared__ float asw[4][Q_];
  size_t rowp = (size_t)b * P_ + p;
  if (tid < H_) {
    p1s[tid] = p1[rowp * H_ + tid];
    pmps[tid] = pmp[rowp * H_ + tid];
  }
  if (tid < H2_) pbs[tid] = pasWb[rowp * H2_ + tid];
  if (tid < Q_) ssc[2][tid] = scd[rowp * Q_ + tid];
  __syncthreads();
  {
    int q = tid >> 2, part = tid & 3;
    const float* q1r = q1 + ((size_t)b * Q_ + q) * H_;
    const float* pmqr = pmq + ((size_t)b * Q_ + q) * H_;
    const float* qr = qry + ((size_t)b * Q_ + q) * H2_;
    float s_c = 0.f, s_m = 0.f, s_b = 0.f;
    int h0 = part * 32;
#pragma unroll 4
    for (int i = 0; i < 32; ++i) {
      int h = h0 + i;
      s_c += fast_tanh(p1s[h] + q1r[h]) * vc[h];
      s_m += fast_tanh(pmqr[h] - pmps[h]) * vm[h];
    }
    int d0 = part * 64;
#pragma unroll 4
    for (int i = 0; i < 64; ++i) s_b += pbs[d0 + i] * qr[d0 + i];
    s_c += __shfl_xor(s_c, 1); s_c += __shfl_xor(s_c, 2);
    s_m += __shfl_xor(s_m, 1); s_m += __shfl_xor(s_m, 2);
    s_b += __shfl_xor(s_b, 1); s_b += __shfl_xor(s_b, 2);
    if (part == 0) { ssc[0][q] = s_c; ssc[1][q] = s_b; ssc[3][q] = s_m; }
  }
  __syncthreads();
  {
    int wv = tid >> 6, lane = tid & 63;
    float s = (qmask[b * Q_ + lane] != 0) ? ssc[wv][lane] : -1e30f;
    float mx = s;
    for (int m = 32; m >= 1; m >>= 1) mx = fmaxf(mx, __shfl_xor(mx, m));
    float e = __expf(s - mx);
    float sum = e;
    for (int m = 32; m >= 1; m >>= 1) sum += __shfl_xor(sum, m);
    asw[wv][lane] = e / sum;
  }
  __syncthreads();
  {
    int d = tid;
    const float* qcol = qry + (size_t)b * Q_ * H2_ + d;
    float o0 = 0.f, o1 = 0.f, o2 = 0.f, o3 = 0.f;
#pragma unroll 8
    for (int q2 = 0; q2 < Q_; ++q2) {
      float qv = qcol[(size_t)q2 * H2_];
      o0 += asw[0][q2] * qv;
      o1 += asw[1][q2] * qv;
      o2 += asw[2][q2] * qv;
      o3 += asw[3][q2] * qv;
    }
    _Float16* arow = agg_h + rowp * H10_;
    arow[d] = (_Float16)pas[rowp * H2_ + d];
    arow[256 + d] = (_Float16)o0;
    arow[512 + d] = (_Float16)o1;
    arow[768 + d] = (_Float16)o2;
    arow[1024 + d] = (_Float16)o3;
  }
}

// ---------------- gi = agg_in @ gWih + gbih (both dirs), f16 MFMA ----------------
__global__ __launch_bounds__(256) void k_gi(
    const _Float16* __restrict__ agg_h, const _Float16* __restrict__ gih_sw,
    const float* __restrict__ gbih_f, const float* __restrict__ gbih_b,
    float* __restrict__ gi_f, float* __restrict__ gi_b) {
  int dir = blockIdx.y;
  const float* gbih = dir ? gbih_b : gbih_f;
  float* gi = dir ? gi_b : gi_f;
  int tid = threadIdx.x;
  int w = tid >> 6, l = tid & 63;
  int p0 = blockIdx.x * 64 + w * 16;
  const _Float16* arow = agg_h + ((size_t)(p0 + (l & 15))) * H10_ + ((l >> 4) << 2);
  const _Float16* bbase = gih_sw + (size_t)dir * 80 * 24 * 64 * 4 + (size_t)l * 4;
  f32x4 acc[24] = {};
  for (int ks = 0; ks < 80; ++ks) {
    half4_t a = *(const half4_t*)(arow + ks * 16);
    const _Float16* bkt = bbase + (size_t)ks * 24 * 64 * 4;
#pragma unroll
    for (int ht = 0; ht < 24; ++ht) {
      half4_t bf = *(const half4_t*)(bkt + (size_t)ht * 64 * 4);
      acc[ht] = __builtin_amdgcn_mfma_f32_16x16x16f16(a, bf, acc[ht], 0, 0, 0);
    }
  }
  int r0 = p0 + ((l >> 4) << 2);
#pragma unroll
  for (int ht = 0; ht < 24; ++ht) {
    int col = ht * 16 + (l & 15);
    float bias = gbih[col];
#pragma unroll
    for (int j = 0; j < 4; ++j)
      gi[((size_t)(r0 + j)) * G_ + col] = acc[ht][j] + bias;
  }
}

// ---------------- GRU scan v6: MFMA recurrence, no shuffle reduce ----------------
// 16 blocks x 512 thr (8 waves = 2/SIMD). Wave w owns j in [w*16, w*16+16):
// 3 gate accumulators x 8 dependent mfma_16x16x16f16 (A = h broadcast to all rows,
// so every lane's acc[0] = gh[col=l&15]). Gates computed by ALL lanes (redundant,
// no divergence); lanes l<16 write h & agg. One raw barrier per step.
__global__ __attribute__((amdgpu_waves_per_eu(2, 2))) __launch_bounds__(512) void k_gru(
    const float* __restrict__ gi_f, const float* __restrict__ gi_b,
    const _Float16* __restrict__ whh_sw,
    const float* __restrict__ bhh_f, const float* __restrict__ bhh_b,
    float* __restrict__ agg) {
  int dir = blockIdx.x >> 3;
  int bb = blockIdx.x & 7;
  const float* gi = dir ? gi_b : gi_f;
  const float* bhh = dir ? bhh_b : bhh_f;
  int tid = threadIdx.x;
  int w = tid >> 6, l = tid & 63;
  int j = w * 16 + (l & 15);
  // one-time B-fragment load: gate g, k-tile ks -> col-tile ct = g*8+w
  half4_t Bf[3][8];
  {
    const _Float16* wb = whh_sw + (size_t)dir * 8 * 24 * 64 * 4;
#pragma unroll
    for (int g = 0; g < 3; ++g) {
      int ct = g * 8 + w;
#pragma unroll
      for (int ks = 0; ks < 8; ++ks)
        Bf[g][ks] = *(const half4_t*)(wb + (((size_t)(ks * 24 + ct)) * 64 + l) * 4);
    }
  }
  float bhr = bhh[j], bhz = bhh[128 + j], bhn = bhh[256 + j];
  __shared__ __align__(16) _Float16 hsbuf[2][H_];
  if (tid < H_) hsbuf[0][tid] = (_Float16)0.f;
  float hprev = 0.f;
  int p = dir ? (P_ - 1) : 0;
  int dp = dir ? -1 : 1;
  size_t gbase = (size_t)bb * P_;
  // 2-deep gi prefetch (all lanes, broadcast within 16-lane groups)
  float g0r, g0z, g0n, g1r, g1z, g1n;
  {
    size_t r0 = (gbase + p) * G_;
    g0r = gi[r0 + j]; g0z = gi[r0 + 128 + j]; g0n = gi[r0 + 256 + j];
    size_t r1 = (gbase + p + dp) * G_;
    g1r = gi[r1 + j]; g1z = gi[r1 + 128 + j]; g1n = gi[r1 + 256 + j];
  }
  GRUBAR();
  int cur = 0;
  int ao = (l >> 4) << 2;  // element offset within k-tile
  for (int t = 0; t < P_; ++t) {
    float g2r = 0.f, g2z = 0.f, g2n = 0.f;
    if (t + 2 < P_) {
      size_t r2 = (gbase + p + 2 * dp) * G_;
      g2r = gi[r2 + j]; g2z = gi[r2 + 128 + j]; g2n = gi[r2 + 256 + j];
    }
    // A-fragments: h[ks*16 + ao .. +4) — broadcast b64 reads
    const _Float16* hb = hsbuf[cur];
    half4_t ha[8];
#pragma unroll
    for (int ks = 0; ks < 8; ++ks) ha[ks] = *(const half4_t*)(hb + ks * 16 + ao);
    f32x4 ar = {}, az = {}, an = {};
#pragma unroll
    for (int ks = 0; ks < 8; ++ks) {
      ar = __builtin_amdgcn_mfma_f32_16x16x16f16(ha[ks], Bf[0][ks], ar, 0, 0, 0);
      az = __builtin_amdgcn_mfma_f32_16x16x16f16(ha[ks], Bf[1][ks], az, 0, 0, 0);
      an = __builtin_amdgcn_mfma_f32_16x16x16f16(ha[ks], Bf[2][ks], an, 0, 0, 0);
    }
    // every lane's acc[0] = gh for col l&15 (all A-rows identical)
    float r = fast_sigm(g0r + ar[0] + bhr);
    float z = fast_sigm(g0z + az[0] + bhz);
    float nn = fast_tanh(g0n + r * (an[0] + bhn));
    float hnew = (1.f - z) * nn + z * hprev;
    hprev = hnew;
    if (l < 16) {
      hsbuf[cur ^ 1][j] = (_Float16)hnew;
      agg[(size_t)(gbase + p) * H2_ + dir * H_ + j] = hnew;
    }
    GRUBAR();
    cur ^= 1;
    g0r = g1r; g0z = g1z; g0n = g1n;
    g1r = g2r; g1z = g2z; g1n = g2n;
    p += dp;
  }
}

// ---------------- sp raw scores ----------------
__global__ __launch_bounds__(128) void k_spscore(
    const float* __restrict__ agg, const float* __restrict__ wp1,
    const float* __restrict__ rqw2, const float* __restrict__ vp,
    float* __restrict__ spraw) {
  int bx = blockIdx.x;
  int b = bx >> 9, p = bx & (P_ - 1);
  int h = threadIdx.x;
  const float* ar = agg + ((size_t)b * P_ + p) * H2_;
  float acc = rqw2[b * H_ + h];
#pragma unroll 8
  for (int d = 0; d < H2_; ++d) acc += ar[d] * wp1[(size_t)d * H_ + h];
  float v = fast_tanh(acc) * vp[h];
  for (int m = 32; m >= 1; m >>= 1) v += __shfl_xor(v, m);
  __shared__ float par[2];
  if ((h & 63) == 0) par[h >> 6] = v;
  __syncthreads();
  if (h == 0) spraw[bx] = par[0] + par[1];
}

// ---------------- final head: sp softmax, rp, logits, out softmax ----------------
__global__ __launch_bounds__(256) void k_final(
    const float* __restrict__ spraw, const int* __restrict__ pmask,
    const float* __restrict__ agg, const float* __restrict__ predict_w,
    const float* __restrict__ alters, float* __restrict__ out) {
  int b = blockIdx.x;
  int t = threadIdx.x;
  __shared__ float sp[P_];
  __shared__ float red[4];
  __shared__ float rpr[H2_];
  __shared__ float rpl[H_];
  __shared__ float lg[3];
  float s0 = (pmask[b * P_ + t] != 0) ? spraw[b * P_ + t] : -1e30f;
  float s1 = (pmask[b * P_ + 256 + t] != 0) ? spraw[b * P_ + 256 + t] : -1e30f;
  float mx = fmaxf(s0, s1);
  for (int m = 32; m >= 1; m >>= 1) mx = fmaxf(mx, __shfl_xor(mx, m));
  if ((t & 63) == 0) red[t >> 6] = mx;
  __syncthreads();
  mx = fmaxf(fmaxf(red[0], red[1]), fmaxf(red[2], red[3]));
  float e0 = __expf(s0 - mx), e1 = __expf(s1 - mx);
  float ss = e0 + e1;
  for (int m = 32; m >= 1; m >>= 1) ss += __shfl_xor(ss, m);
  __syncthreads();
  if ((t & 63) == 0) red[t >> 6] = ss;
  __syncthreads();
  float tot = red[0] + red[1] + red[2] + red[3];
  float inv = 1.f / tot;
  sp[t] = e0 * inv;
  sp[256 + t] = e1 * inv;
  __syncthreads();
  {
    float acc = 0.f;
    const float* acol = agg + (size_t)b * P_ * H2_ + t;
#pragma unroll 8
    for (int p = 0; p < P_; ++p) acc += sp[p] * acol[(size_t)p * H2_];
    rpr[t] = acc;
  }
  __syncthreads();
  if (t < H_) {
    float acc = 0.f;
#pragma unroll 4
    for (int d = 0; d < H2_; ++d) acc += rpr[d] * predict_w[(size_t)d * H_ + t];
    rpl[t] = (acc > 0.f) ? acc : 0.01f * acc;
  }
  __syncthreads();
  if (t < 3) {
    float acc = 0.f;
    const float* al = alters + ((size_t)(b * 3 + t)) * H_;
    for (int h = 0; h < H_; ++h) acc += al[h] * rpl[h];
    lg[t] = acc;
  }
  __syncthreads();
  if (t == 0) {
    float m3 = fmaxf(lg[0], fmaxf(lg[1], lg[2]));
    float x0 = __expf(lg[0] - m3), x1 = __expf(lg[1] - m3), x2 = __expf(lg[2] - m3);
    float is = 1.f / (x0 + x1 + x2);
    out[b * 3 + 0] = x0 * is;
    out[b * 3 + 1] = x1 * is;
    out[b * 3 + 2] = x2 * is;
  }
}

extern "C" void kernel_launch(void* const* d_in, const int* in_sizes, int n_in,
                              void* d_out, int out_size, void* d_ws, size_t ws_size,
                              hipStream_t stream) {
  (void)in_sizes; (void)n_in; (void)out_size; (void)ws_size;
  const float* pas = (const float*)d_in[0];
  const float* qry = (const float*)d_in[1];
  const float* alt1 = (const float*)d_in[2];
  const float* alt2 = (const float*)d_in[3];
  const float* alt3 = (const float*)d_in[4];
  const float* a_att_w = (const float*)d_in[5];
  const float* Wc1 = (const float*)d_in[6];
  const float* Wc2 = (const float*)d_in[7];
  const float* vc = (const float*)d_in[8];
  const float* Wb = (const float*)d_in[9];
  const float* Wd = (const float*)d_in[10];
  const float* vd = (const float*)d_in[11];
  const float* Wm = (const float*)d_in[12];
  const float* vm = (const float*)d_in[13];
  const float* wq = (const float*)d_in[14];
  const float* vq = (const float*)d_in[15];
  const float* wp1 = (const float*)d_in[16];
  const float* wp2 = (const float*)d_in[17];
  const float* vp = (const float*)d_in[18];
  const float* predict_w = (const float*)d_in[19];
  const float* gWih_f = (const float*)d_in[20];
  const float* gWhh_f = (const float*)d_in[21];
  const float* gbih_f = (const float*)d_in[22];
  const float* gbhh_f = (const float*)d_in[23];
  const float* gWih_b = (const float*)d_in[24];
  const float* gWhh_b = (const float*)d_in[25];
  const float* gbih_b = (const float*)d_in[26];
  const float* gbhh_b = (const float*)d_in[27];
  const int* pmask = (const int*)d_in[28];
  const int* qmask = (const int*)d_in[29];
  const int* m1 = (const int*)d_in[30];
  const int* m2 = (const int*)d_in[31];
  const int* m3 = (const int*)d_in[32];
  float* out = (float*)d_out;

  char* ws = (char*)d_ws;
  size_t off = 0;
  auto alloc_f = [&](size_t n) {
    float* ptr = (float*)(ws + off);
    off += n * 4;
    off = (off + 255) & ~(size_t)255;
    return ptr;
  };
  float* alters = alloc_f((size_t)B_ * 3 * H_);
  float* p1 = alloc_f((size_t)B_ * P_ * H_);
  float* q1 = alloc_f((size_t)B_ * Q_ * H_);
  float* pmp = alloc_f((size_t)B_ * P_ * H_);
  float* pmq = alloc_f((size_t)B_ * Q_ * H_);
  float* pasWb = alloc_f((size_t)B_ * P_ * H2_);
  float* scd = alloc_f((size_t)B_ * P_ * Q_);
  float* gi_f = alloc_f((size_t)B_ * P_ * G_);
  float* gi_b = alloc_f((size_t)B_ * P_ * G_);
  float* agg = alloc_f((size_t)B_ * P_ * H2_);
  float* sjraw = alloc_f((size_t)B_ * Q_);
  float* rqw2 = alloc_f((size_t)B_ * H_);
  float* spraw = alloc_f((size_t)B_ * P_);
  auto alloc_h = [&](size_t n) {
    _Float16* ptr = (_Float16*)(ws + off);
    off += n * 2;
    off = (off + 255) & ~(size_t)255;
    return ptr;
  };
  _Float16* wd_sw = alloc_h((size_t)16 * 8 * 64 * 4);
  _Float16* gih_sw = alloc_h((size_t)2 * 80 * 24 * 64 * 4);
  _Float16* agg_h = alloc_h((size_t)B_ * P_ * H10_);
  _Float16* whh_sw = alloc_h((size_t)2 * 8 * 24 * 64 * 4);

  k_pre<<<NB_PRE, 256, 0, stream>>>(
      alt1, alt2, alt3, m1, m2, m3, a_att_w, alters,
      Wd, wd_sw, gWih_f, gWih_b, gih_sw, gWhh_f, gWhh_b, whh_sw,
      pas, qry, Wc1, p1, Wc2, q1, Wm, pmp, pmq, Wb, pasWb, wq, vq, sjraw);
  k_scd_rq<<<B_ * Q_ * 8 + B_, 256, 0, stream>>>(
      pas, qry, wd_sw, vd, scd, sjraw, qmask, wp2, rqw2);
  k_attend<<<B_ * P_, 256, 0, stream>>>(pas, qry, p1, q1, pmp, pmq, pasWb, scd, vc, vm, qmask, agg_h);
  k_gi<<<dim3(64, 2), 256, 0, stream>>>(agg_h, gih_sw, gbih_f, gbih_b, gi_f, gi_b);
  k_gru<<<16, 512, 0, stream>>>(gi_f, gi_b, whh_sw, gbhh_f, gbhh_b, agg);
  k_spscore<<<B_ * P_, 128, 0, stream>>>(agg, wp1, rqw2, vp, spraw);
  k_final<<<B_, 256, 0, stream>>>(spraw, pmask, agg, predict_w, alters, out);
}

// Round 7
// 750.102 us; speedup vs baseline: 1.1367x; 1.1367x over previous
//
#include <hip/hip_runtime.h>

#define B_ 8
#define P_ 512
#define Q_ 64
#define A_ 16
#define H_ 128
#define H2_ 256
#define H10_ 1280
#define G_ 384

typedef float f32x4 __attribute__((ext_vector_type(4)));
typedef _Float16 half4_t __attribute__((ext_vector_type(4)));
typedef _Float16 half2_t __attribute__((ext_vector_type(2)));
typedef _Float16 half8_t __attribute__((ext_vector_type(8)));

// division-free transcendentals (v_exp_f32 is exp2; v_rcp_f32 ~1e-7 rel err)
__device__ __forceinline__ float fast_tanh(float x) {
  return 1.f - 2.f * __builtin_amdgcn_rcpf(1.f + __builtin_amdgcn_exp2f(2.88539008f * x));
}
__device__ __forceinline__ float fast_sigm(float x) {
  return __builtin_amdgcn_rcpf(1.f + __builtin_amdgcn_exp2f(-1.44269504f * x));
}

// raw barrier: LDS drain only — vmcnt (global prefetch/stores) stays in flight
#define GRUBAR() asm volatile("s_waitcnt lgkmcnt(0)\n\ts_barrier" ::: "memory")

// ================= fused preprocessing mega-kernel =================
// blockIdx ranges:
//  [0,24)        alters pooling
//  [24,152)      prep_frag Wd        (32768 elems)
//  [152,2072)    prep_frag gWih_f    (491520)
//  [2072,3992)   prep_frag gWih_b
//  [3992,4184)   prep_frag32 gWhh_f  (49152)  -> K=32 MFMA B-frag layout
//  [4184,4376)   prep_frag32 gWhh_b
//  [4376,4888)   gemm4 pas@Wc1 -> p1
//  [4888,4952)   gemm4 qry@Wc2 -> q1
//  [4952,5464)   gemm4 pas@Wm  -> pmp
//  [5464,5528)   gemm4 qry@Wm  -> pmq
//  [5528,6552)   gemm4 pas@Wb  -> pasWb
//  [6552,6808)   qscore (2 rows/block)
#define NB_PRE 6808

__device__ __forceinline__ void prep_frag_body(int idx, const float* __restrict__ W,
                                               _Float16* __restrict__ out, int KT, int HT, int N) {
  int total = KT * HT * 64 * 4;
  if (idx >= total) return;
  int e = idx & 3;
  int l = (idx >> 2) & 63;
  int rest = idx >> 8;
  int ht = rest % HT;
  int ks = rest / HT;
  int k = ks * 16 + ((l >> 4) << 2) + e;
  int n = ht * 16 + (l & 15);
  out[idx] = (_Float16)W[(size_t)k * N + n];
}

// K=32 fragment (16x16x32 f16): lane l elem e -> k = ks*32 + (l>>4)*8 + e.
// Same self-consistent mapping used when loading A from LDS, so any HW k-perm
// cancels (applied to both operands of the contraction).
__device__ __forceinline__ void prep_frag32_body(int idx, const float* __restrict__ W,
                                                 _Float16* __restrict__ out, int KT, int HT, int N) {
  int total = KT * HT * 64 * 8;
  if (idx >= total) return;
  int e = idx & 7;
  int l = (idx >> 3) & 63;
  int rest = idx >> 9;
  int ht = rest % HT;
  int ks = rest / HT;
  int k = ks * 32 + ((l >> 4) << 3) + e;
  int n = ht * 16 + (l & 15);
  out[idx] = (_Float16)W[(size_t)k * N + n];
}

__device__ __forceinline__ void gemm4_body(int id, const float* __restrict__ A,
                                           const float* __restrict__ W, float* __restrict__ C,
                                           int M, int K, int N) {
  int total = (M >> 2) * N;
  if (id >= total) return;
  int n = id % N;
  int m0 = (id / N) << 2;
  const float* a0 = A + (size_t)m0 * K;
  const float* a1 = a0 + K;
  const float* a2 = a1 + K;
  const float* a3 = a2 + K;
  float c0 = 0.f, c1 = 0.f, c2 = 0.f, c3 = 0.f;
#pragma unroll 4
  for (int k = 0; k < K; ++k) {
    float wv = W[(size_t)k * N + n];
    c0 += a0[k] * wv; c1 += a1[k] * wv; c2 += a2[k] * wv; c3 += a3[k] * wv;
  }
  C[(size_t)m0 * N + n] = c0;
  C[(size_t)(m0 + 1) * N + n] = c1;
  C[(size_t)(m0 + 2) * N + n] = c2;
  C[(size_t)(m0 + 3) * N + n] = c3;
}

__global__ __launch_bounds__(256) void k_pre(
    const float* __restrict__ a1, const float* __restrict__ a2, const float* __restrict__ a3,
    const int* __restrict__ m1, const int* __restrict__ m2, const int* __restrict__ m3,
    const float* __restrict__ a_att_w, float* __restrict__ alters,
    const float* __restrict__ Wd, _Float16* __restrict__ wd_sw,
    const float* __restrict__ gWih_f, const float* __restrict__ gWih_b,
    _Float16* __restrict__ gih_sw,
    const float* __restrict__ gWhh_f, const float* __restrict__ gWhh_b,
    _Float16* __restrict__ whh_sw,
    const float* __restrict__ pas, const float* __restrict__ qry,
    const float* __restrict__ Wc1, float* __restrict__ p1,
    const float* __restrict__ Wc2, float* __restrict__ q1,
    const float* __restrict__ Wm, float* __restrict__ pmp, float* __restrict__ pmq,
    const float* __restrict__ Wb, float* __restrict__ pasWb,
    const float* __restrict__ wq, const float* __restrict__ vq, float* __restrict__ sjraw) {
  int bx = blockIdx.x;
  int tid = threadIdx.x;
  if (bx < 24) {
    // ---- alt pooling ----
    int b = bx / 3, i = bx % 3;
    const float* x = (i == 0) ? a1 : (i == 1) ? a2 : a3;
    const int* mk = (i == 0) ? m1 : (i == 1) ? m2 : m3;
    __shared__ float sc[A_];
    __shared__ float sw[A_];
    if (tid < A_) {
      const float* row = x + ((size_t)(b * A_ + tid)) * H_;
      float acc = 0.f;
      for (int h = 0; h < H_; ++h) acc += row[h] * a_att_w[h];
      sc[tid] = (mk[b * A_ + tid] != 0) ? acc : -1e30f;
    }
    __syncthreads();
    if (tid == 0) {
      float mx = -1e30f;
      for (int a = 0; a < A_; ++a) mx = fmaxf(mx, sc[a]);
      float s = 0.f;
      for (int a = 0; a < A_; ++a) { float e = __expf(sc[a] - mx); sw[a] = e; s += e; }
      float inv = 1.f / s;
      for (int a = 0; a < A_; ++a) sw[a] *= inv;
    }
    __syncthreads();
    if (tid < H_) {
      float acc = 0.f;
      for (int a = 0; a < A_; ++a) acc += sw[a] * x[((size_t)(b * A_ + a)) * H_ + tid];
      alters[((size_t)(b * 3 + i)) * H_ + tid] = acc;
    }
    return;
  }
  bx -= 24;
  if (bx < 128) { prep_frag_body(bx * 256 + tid, Wd, wd_sw, 16, 8, H_); return; }
  bx -= 128;
  if (bx < 1920) { prep_frag_body(bx * 256 + tid, gWih_f, gih_sw, 80, 24, G_); return; }
  bx -= 1920;
  if (bx < 1920) {
    prep_frag_body(bx * 256 + tid, gWih_b, gih_sw + (size_t)80 * 24 * 64 * 4, 80, 24, G_);
    return;
  }
  bx -= 1920;
  if (bx < 192) { prep_frag32_body(bx * 256 + tid, gWhh_f, whh_sw, 4, 24, G_); return; }
  bx -= 192;
  if (bx < 192) {
    prep_frag32_body(bx * 256 + tid, gWhh_b, whh_sw + (size_t)4 * 24 * 64 * 8, 4, 24, G_);
    return;
  }
  bx -= 192;
  if (bx < 512) { gemm4_body(bx * 256 + tid, pas, Wc1, p1, B_ * P_, H2_, H_); return; }
  bx -= 512;
  if (bx < 64) { gemm4_body(bx * 256 + tid, qry, Wc2, q1, B_ * Q_, H2_, H_); return; }
  bx -= 64;
  if (bx < 512) { gemm4_body(bx * 256 + tid, pas, Wm, pmp, B_ * P_, H2_, H_); return; }
  bx -= 512;
  if (bx < 64) { gemm4_body(bx * 256 + tid, qry, Wm, pmq, B_ * Q_, H2_, H_); return; }
  bx -= 64;
  if (bx < 1024) { gemm4_body(bx * 256 + tid, pas, Wb, pasWb, B_ * P_, H2_, H2_); return; }
  bx -= 1024;
  {
    // ---- qscore: 2 rows per block ----
    int rs = tid >> 7;            // row within block
    int h = tid & 127;
    int row = bx * 2 + rs;
    const float* qr = qry + (size_t)row * H2_;
    float acc = 0.f;
#pragma unroll 4
    for (int d = 0; d < H2_; ++d) acc += qr[d] * wq[(size_t)d * H_ + h];
    float v = fast_tanh(acc) * vq[h];
    for (int m = 32; m >= 1; m >>= 1) v += __shfl_xor(v, m);
    __shared__ float par[2][2];
    if ((h & 63) == 0) par[rs][h >> 6] = v;
    __syncthreads();
    if (h == 0) sjraw[row] = par[rs][0] + par[rs][1];
  }
}

// ================= sc_d scores (MFMA) + rq fused launch =================
__global__ __launch_bounds__(256) void k_scd_rq(
    const float* __restrict__ pas, const float* __restrict__ qry,
    const _Float16* __restrict__ wd_sw, const float* __restrict__ vd,
    float* __restrict__ scd,
    const float* __restrict__ sjraw, const int* __restrict__ qmask,
    const float* __restrict__ wp2, float* __restrict__ rqw2) {
  int bx0 = blockIdx.x;
  int tid = threadIdx.x;
  if (bx0 < B_ * Q_ * 8) {
    int pt = bx0 & 7;
    int rem = bx0 >> 3;
    int q = rem & (Q_ - 1);
    int b = rem >> 6;
    int w = tid >> 6, l = tid & 63;
    __shared__ __align__(16) float qs[H2_];
    __shared__ float vds[H_];
    if (tid < H2_) qs[tid] = qry[((size_t)(b * Q_ + q)) * H2_ + tid];
    if (tid < H_) vds[tid] = vd[tid];
    __syncthreads();
    int arow = pt * 64 + w * 16 + (l & 15);
    const float* prow = pas + ((size_t)(b * P_) + arow) * H2_;
    int ko = (l >> 4) << 2;
    f32x4 acc[8] = {};
#pragma unroll
    for (int ks = 0; ks < 16; ++ks) {
      int j0 = ks * 16 + ko;
      float4 pa = *(const float4*)(prow + j0);
      float4 qa = *(const float4*)(qs + j0);
      half4_t a;
      a[0] = (_Float16)(pa.x * qa.x);
      a[1] = (_Float16)(pa.y * qa.y);
      a[2] = (_Float16)(pa.z * qa.z);
      a[3] = (_Float16)(pa.w * qa.w);
      const _Float16* bb = wd_sw + (((size_t)(ks * 8) * 64) + l) * 4;
#pragma unroll
      for (int ht = 0; ht < 8; ++ht) {
        half4_t bf = *(const half4_t*)(bb + (size_t)ht * 64 * 4);
        acc[ht] = __builtin_amdgcn_mfma_f32_16x16x16f16(a, bf, acc[ht], 0, 0, 0);
      }
    }
    float part[4] = {0.f, 0.f, 0.f, 0.f};
#pragma unroll
    for (int ht = 0; ht < 8; ++ht) {
      float v = vds[ht * 16 + (l & 15)];
#pragma unroll
      for (int j = 0; j < 4; ++j) part[j] += v * fast_tanh(acc[ht][j]);
    }
#pragma unroll
    for (int j = 0; j < 4; ++j) {
      float s = part[j];
      s += __shfl_xor(s, 1);
      s += __shfl_xor(s, 2);
      s += __shfl_xor(s, 4);
      s += __shfl_xor(s, 8);
      part[j] = s;
    }
    if ((l & 15) == 0) {
      int pr = pt * 64 + w * 16 + ((l >> 4) << 2);
#pragma unroll
      for (int j = 0; j < 4; ++j)
        scd[((size_t)b * P_ + pr + j) * Q_ + q] = part[j];
    }
    return;
  }
  {
    // ---- rq + rq@wp2 ----
    int b = bx0 - B_ * Q_ * 8;
    int t = tid;
    __shared__ float sj[Q_];
    __shared__ float rql[H2_];
    if (t < Q_) {
      float s = (qmask[b * Q_ + t] != 0) ? sjraw[b * Q_ + t] : -1e30f;
      float mx = s;
      for (int m = 32; m >= 1; m >>= 1) mx = fmaxf(mx, __shfl_xor(mx, m));
      float e = __expf(s - mx);
      float sum = e;
      for (int m = 32; m >= 1; m >>= 1) sum += __shfl_xor(sum, m);
      sj[t] = e / sum;
    }
    __syncthreads();
    {
      float acc = 0.f;
      const float* qcol = qry + (size_t)b * Q_ * H2_ + t;
#pragma unroll 8
      for (int q = 0; q < Q_; ++q) acc += sj[q] * qcol[(size_t)q * H2_];
      rql[t] = acc;
    }
    __syncthreads();
    if (t < H_) {
      float acc = 0.f;
#pragma unroll 4
      for (int d = 0; d < H2_; ++d) acc += rql[d] * wp2[(size_t)d * H_ + t];
      rqw2[b * H_ + t] = acc;
    }
  }
}

// ---------------- fused per-(b,p): sc_c/sc_b/sc_m scores + 4 masked softmaxes + attends ----------------
__global__ __launch_bounds__(256) void k_attend(
    const float* __restrict__ pas, const float* __restrict__ qry,
    const float* __restrict__ p1, const float* __restrict__ q1,
    const float* __restrict__ pmp, const float* __restrict__ pmq,
    const float* __restrict__ pasWb, const float* __restrict__ scd,
    const float* __restrict__ vc, const float* __restrict__ vm,
    const int* __restrict__ qmask, _Float16* __restrict__ agg_h) {
  int bx = blockIdx.x;
  int b = bx >> 9, p = bx & (P_ - 1);
  int tid = threadIdx.x;
  __shared__ float p1s[H_], pmps[H_];
  __shared__ float pbs[H2_];
  __shared__ float ssc[4][Q_];
  __shared__ float asw[4][Q_];
  size_t rowp = (size_t)b * P_ + p;
  if (tid < H_) {
    p1s[tid] = p1[rowp * H_ + tid];
    pmps[tid] = pmp[rowp * H_ + tid];
  }
  if (tid < H2_) pbs[tid] = pasWb[rowp * H2_ + tid];
  if (tid < Q_) ssc[2][tid] = scd[rowp * Q_ + tid];
  __syncthreads();
  {
    int q = tid >> 2, part = tid & 3;
    const float* q1r = q1 + ((size_t)b * Q_ + q) * H_;
    const float* pmqr = pmq + ((size_t)b * Q_ + q) * H_;
    const float* qr = qry + ((size_t)b * Q_ + q) * H2_;
    float s_c = 0.f, s_m = 0.f, s_b = 0.f;
    int h0 = part * 32;
#pragma unroll 4
    for (int i = 0; i < 32; ++i) {
      int h = h0 + i;
      s_c += fast_tanh(p1s[h] + q1r[h]) * vc[h];
      s_m += fast_tanh(pmqr[h] - pmps[h]) * vm[h];
    }
    int d0 = part * 64;
#pragma unroll 4
    for (int i = 0; i < 64; ++i) s_b += pbs[d0 + i] * qr[d0 + i];
    s_c += __shfl_xor(s_c, 1); s_c += __shfl_xor(s_c, 2);
    s_m += __shfl_xor(s_m, 1); s_m += __shfl_xor(s_m, 2);
    s_b += __shfl_xor(s_b, 1); s_b += __shfl_xor(s_b, 2);
    if (part == 0) { ssc[0][q] = s_c; ssc[1][q] = s_b; ssc[3][q] = s_m; }
  }
  __syncthreads();
  {
    int wv = tid >> 6, lane = tid & 63;
    float s = (qmask[b * Q_ + lane] != 0) ? ssc[wv][lane] : -1e30f;
    float mx = s;
    for (int m = 32; m >= 1; m >>= 1) mx = fmaxf(mx, __shfl_xor(mx, m));
    float e = __expf(s - mx);
    float sum = e;
    for (int m = 32; m >= 1; m >>= 1) sum += __shfl_xor(sum, m);
    asw[wv][lane] = e / sum;
  }
  __syncthreads();
  {
    int d = tid;
    const float* qcol = qry + (size_t)b * Q_ * H2_ + d;
    float o0 = 0.f, o1 = 0.f, o2 = 0.f, o3 = 0.f;
#pragma unroll 8
    for (int q2 = 0; q2 < Q_; ++q2) {
      float qv = qcol[(size_t)q2 * H2_];
      o0 += asw[0][q2] * qv;
      o1 += asw[1][q2] * qv;
      o2 += asw[2][q2] * qv;
      o3 += asw[3][q2] * qv;
    }
    _Float16* arow = agg_h + rowp * H10_;
    arow[d] = (_Float16)pas[rowp * H2_ + d];
    arow[256 + d] = (_Float16)o0;
    arow[512 + d] = (_Float16)o1;
    arow[768 + d] = (_Float16)o2;
    arow[1024 + d] = (_Float16)o3;
  }
}

// ---------------- gi = agg_in @ gWih + gbih (both dirs), f16 MFMA ----------------
__global__ __launch_bounds__(256) void k_gi(
    const _Float16* __restrict__ agg_h, const _Float16* __restrict__ gih_sw,
    const float* __restrict__ gbih_f, const float* __restrict__ gbih_b,
    float* __restrict__ gi_f, float* __restrict__ gi_b) {
  int dir = blockIdx.y;
  const float* gbih = dir ? gbih_b : gbih_f;
  float* gi = dir ? gi_b : gi_f;
  int tid = threadIdx.x;
  int w = tid >> 6, l = tid & 63;
  int p0 = blockIdx.x * 64 + w * 16;
  const _Float16* arow = agg_h + ((size_t)(p0 + (l & 15))) * H10_ + ((l >> 4) << 2);
  const _Float16* bbase = gih_sw + (size_t)dir * 80 * 24 * 64 * 4 + (size_t)l * 4;
  f32x4 acc[24] = {};
  for (int ks = 0; ks < 80; ++ks) {
    half4_t a = *(const half4_t*)(arow + ks * 16);
    const _Float16* bkt = bbase + (size_t)ks * 24 * 64 * 4;
#pragma unroll
    for (int ht = 0; ht < 24; ++ht) {
      half4_t bf = *(const half4_t*)(bkt + (size_t)ht * 64 * 4);
      acc[ht] = __builtin_amdgcn_mfma_f32_16x16x16f16(a, bf, acc[ht], 0, 0, 0);
    }
  }
  int r0 = p0 + ((l >> 4) << 2);
#pragma unroll
  for (int ht = 0; ht < 24; ++ht) {
    int col = ht * 16 + (l & 15);
    float bias = gbih[col];
#pragma unroll
    for (int j = 0; j < 4; ++j)
      gi[((size_t)(r0 + j)) * G_ + col] = acc[ht][j] + bias;
  }
}

// ---------------- GRU scan v7: K=32 MFMA, 6 independent 2-deep chains ----------------
// 16 blocks x 512 thr (8 waves = 2/SIMD). Wave w owns j in [w*16, w*16+16):
// per gate, K split into [0,64) and [64,128) accumulators (2 x K=32 MFMA each).
// 6 independent chains of depth 2 -> dep latency hidden by issue interleave.
__global__ __attribute__((amdgpu_waves_per_eu(2, 2))) __launch_bounds__(512) void k_gru(
    const float* __restrict__ gi_f, const float* __restrict__ gi_b,
    const _Float16* __restrict__ whh_sw,
    const float* __restrict__ bhh_f, const float* __restrict__ bhh_b,
    float* __restrict__ agg) {
  int dir = blockIdx.x >> 3;
  int bb = blockIdx.x & 7;
  const float* gi = dir ? gi_b : gi_f;
  const float* bhh = dir ? bhh_b : bhh_f;
  int tid = threadIdx.x;
  int w = tid >> 6, l = tid & 63;
  int j = w * 16 + (l & 15);
  // one-time B-fragment load: gate g, k-tile ks(0..3, K=32 each) -> col-tile g*8+w
  half8_t Bf[3][4];
  {
    const _Float16* wb = whh_sw + (size_t)dir * 4 * 24 * 64 * 8;
#pragma unroll
    for (int g = 0; g < 3; ++g) {
      int ct = g * 8 + w;
#pragma unroll
      for (int ks = 0; ks < 4; ++ks)
        Bf[g][ks] = *(const half8_t*)(wb + (((size_t)(ks * 24 + ct)) * 64 + l) * 8);
    }
  }
  float bhr = bhh[j], bhz = bhh[128 + j], bhn = bhh[256 + j];
  __shared__ __align__(16) _Float16 hsbuf[2][H_];
  if (tid < H_) hsbuf[0][tid] = (_Float16)0.f;
  float hprev = 0.f;
  int p = dir ? (P_ - 1) : 0;
  int dp = dir ? -1 : 1;
  size_t gbase = (size_t)bb * P_;
  // 2-deep gi prefetch (all lanes, broadcast within 16-lane groups)
  float g0r, g0z, g0n, g1r, g1z, g1n;
  {
    size_t r0 = (gbase + p) * G_;
    g0r = gi[r0 + j]; g0z = gi[r0 + 128 + j]; g0n = gi[r0 + 256 + j];
    size_t r1 = (gbase + p + dp) * G_;
    g1r = gi[r1 + j]; g1z = gi[r1 + 128 + j]; g1n = gi[r1 + 256 + j];
  }
  GRUBAR();
  int cur = 0;
  int ao = (l >> 4) << 3;  // elem offset within K=32 tile (matches prep_frag32)
  for (int t = 0; t < P_; ++t) {
    float g2r = 0.f, g2z = 0.f, g2n = 0.f;
    if (t + 2 < P_) {
      size_t r2 = (gbase + p + 2 * dp) * G_;
      g2r = gi[r2 + j]; g2z = gi[r2 + 128 + j]; g2n = gi[r2 + 256 + j];
    }
    // A-fragments: 4 x ds_read_b128 (16B aligned)
    const _Float16* hb = hsbuf[cur];
    half8_t ha[4];
#pragma unroll
    for (int ks = 0; ks < 4; ++ks) ha[ks] = *(const half8_t*)(hb + ks * 32 + ao);
    // 6 independent chains x 2 links
    f32x4 arL = {}, arH = {}, azL = {}, azH = {}, anL = {}, anH = {};
    arL = __builtin_amdgcn_mfma_f32_16x16x32_f16(ha[0], Bf[0][0], arL, 0, 0, 0);
    azL = __builtin_amdgcn_mfma_f32_16x16x32_f16(ha[0], Bf[1][0], azL, 0, 0, 0);
    anL = __builtin_amdgcn_mfma_f32_16x16x32_f16(ha[0], Bf[2][0], anL, 0, 0, 0);
    arH = __builtin_amdgcn_mfma_f32_16x16x32_f16(ha[2], Bf[0][2], arH, 0, 0, 0);
    azH = __builtin_amdgcn_mfma_f32_16x16x32_f16(ha[2], Bf[1][2], azH, 0, 0, 0);
    anH = __builtin_amdgcn_mfma_f32_16x16x32_f16(ha[2], Bf[2][2], anH, 0, 0, 0);
    arL = __builtin_amdgcn_mfma_f32_16x16x32_f16(ha[1], Bf[0][1], arL, 0, 0, 0);
    azL = __builtin_amdgcn_mfma_f32_16x16x32_f16(ha[1], Bf[1][1], azL, 0, 0, 0);
    anL = __builtin_amdgcn_mfma_f32_16x16x32_f16(ha[1], Bf[2][1], anL, 0, 0, 0);
    arH = __builtin_amdgcn_mfma_f32_16x16x32_f16(ha[3], Bf[0][3], arH, 0, 0, 0);
    azH = __builtin_amdgcn_mfma_f32_16x16x32_f16(ha[3], Bf[1][3], azH, 0, 0, 0);
    anH = __builtin_amdgcn_mfma_f32_16x16x32_f16(ha[3], Bf[2][3], anH, 0, 0, 0);
    float arS = arL[0] + arH[0];
    float azS = azL[0] + azH[0];
    float anS = anL[0] + anH[0];
    // every lane's acc[0] = gh for col l&15 (all A-rows identical)
    float r = fast_sigm(g0r + arS + bhr);
    float z = fast_sigm(g0z + azS + bhz);
    float nn = fast_tanh(g0n + r * (anS + bhn));
    float hnew = (1.f - z) * nn + z * hprev;
    hprev = hnew;
    if (l < 16) {
      hsbuf[cur ^ 1][j] = (_Float16)hnew;
      agg[(size_t)(gbase + p) * H2_ + dir * H_ + j] = hnew;
    }
    GRUBAR();
    cur ^= 1;
    g0r = g1r; g0z = g1z; g0n = g1n;
    g1r = g2r; g1z = g2z; g1n = g2n;
    p += dp;
  }
}

// ---------------- sp raw scores ----------------
__global__ __launch_bounds__(128) void k_spscore(
    const float* __restrict__ agg, const float* __restrict__ wp1,
    const float* __restrict__ rqw2, const float* __restrict__ vp,
    float* __restrict__ spraw) {
  int bx = blockIdx.x;
  int b = bx >> 9, p = bx & (P_ - 1);
  int h = threadIdx.x;
  const float* ar = agg + ((size_t)b * P_ + p) * H2_;
  float acc = rqw2[b * H_ + h];
#pragma unroll 8
  for (int d = 0; d < H2_; ++d) acc += ar[d] * wp1[(size_t)d * H_ + h];
  float v = fast_tanh(acc) * vp[h];
  for (int m = 32; m >= 1; m >>= 1) v += __shfl_xor(v, m);
  __shared__ float par[2];
  if ((h & 63) == 0) par[h >> 6] = v;
  __syncthreads();
  if (h == 0) spraw[bx] = par[0] + par[1];
}

// ---------------- final head: sp softmax, rp, logits, out softmax ----------------
__global__ __launch_bounds__(256) void k_final(
    const float* __restrict__ spraw, const int* __restrict__ pmask,
    const float* __restrict__ agg, const float* __restrict__ predict_w,
    const float* __restrict__ alters, float* __restrict__ out) {
  int b = blockIdx.x;
  int t = threadIdx.x;
  __shared__ float sp[P_];
  __shared__ float red[4];
  __shared__ float rpr[H2_];
  __shared__ float rpl[H_];
  __shared__ float lg[3];
  float s0 = (pmask[b * P_ + t] != 0) ? spraw[b * P_ + t] : -1e30f;
  float s1 = (pmask[b * P_ + 256 + t] != 0) ? spraw[b * P_ + 256 + t] : -1e30f;
  float mx = fmaxf(s0, s1);
  for (int m = 32; m >= 1; m >>= 1) mx = fmaxf(mx, __shfl_xor(mx, m));
  if ((t & 63) == 0) red[t >> 6] = mx;
  __syncthreads();
  mx = fmaxf(fmaxf(red[0], red[1]), fmaxf(red[2], red[3]));
  float e0 = __expf(s0 - mx), e1 = __expf(s1 - mx);
  float ss = e0 + e1;
  for (int m = 32; m >= 1; m >>= 1) ss += __shfl_xor(ss, m);
  __syncthreads();
  if ((t & 63) == 0) red[t >> 6] = ss;
  __syncthreads();
  float tot = red[0] + red[1] + red[2] + red[3];
  float inv = 1.f / tot;
  sp[t] = e0 * inv;
  sp[256 + t] = e1 * inv;
  __syncthreads();
  {
    float acc = 0.f;
    const float* acol = agg + (size_t)b * P_ * H2_ + t;
#pragma unroll 8
    for (int p = 0; p < P_; ++p) acc += sp[p] * acol[(size_t)p * H2_];
    rpr[t] = acc;
  }
  __syncthreads();
  if (t < H_) {
    float acc = 0.f;
#pragma unroll 4
    for (int d = 0; d < H2_; ++d) acc += rpr[d] * predict_w[(size_t)d * H_ + t];
    rpl[t] = (acc > 0.f) ? acc : 0.01f * acc;
  }
  __syncthreads();
  if (t < 3) {
    float acc = 0.f;
    const float* al = alters + ((size_t)(b * 3 + t)) * H_;
    for (int h = 0; h < H_; ++h) acc += al[h] * rpl[h];
    lg[t] = acc;
  }
  __syncthreads();
  if (t == 0) {
    float m3 = fmaxf(lg[0], fmaxf(lg[1], lg[2]));
    float x0 = __expf(lg[0] - m3), x1 = __expf(lg[1] - m3), x2 = __expf(lg[2] - m3);
    float is = 1.f / (x0 + x1 + x2);
    out[b * 3 + 0] = x0 * is;
    out[b * 3 + 1] = x1 * is;
    out[b * 3 + 2] = x2 * is;
  }
}

extern "C" void kernel_launch(void* const* d_in, const int* in_sizes, int n_in,
                              void* d_out, int out_size, void* d_ws, size_t ws_size,
                              hipStream_t stream) {
  (void)in_sizes; (void)n_in; (void)out_size; (void)ws_size;
  const float* pas = (const float*)d_in[0];
  const float* qry = (const float*)d_in[1];
  const float* alt1 = (const float*)d_in[2];
  const float* alt2 = (const float*)d_in[3];
  const float* alt3 = (const float*)d_in[4];
  const float* a_att_w = (const float*)d_in[5];
  const float* Wc1 = (const float*)d_in[6];
  const float* Wc2 = (const float*)d_in[7];
  const float* vc = (const float*)d_in[8];
  const float* Wb = (const float*)d_in[9];
  const float* Wd = (const float*)d_in[10];
  const float* vd = (const float*)d_in[11];
  const float* Wm = (const float*)d_in[12];
  const float* vm = (const float*)d_in[13];
  const float* wq = (const float*)d_in[14];
  const float* vq = (const float*)d_in[15];
  const float* wp1 = (const float*)d_in[16];
  const float* wp2 = (const float*)d_in[17];
  const float* vp = (const float*)d_in[18];
  const float* predict_w = (const float*)d_in[19];
  const float* gWih_f = (const float*)d_in[20];
  const float* gWhh_f = (const float*)d_in[21];
  const float* gbih_f = (const float*)d_in[22];
  const float* gbhh_f = (const float*)d_in[23];
  const float* gWih_b = (const float*)d_in[24];
  const float* gWhh_b = (const float*)d_in[25];
  const float* gbih_b = (const float*)d_in[26];
  const float* gbhh_b = (const float*)d_in[27];
  const int* pmask = (const int*)d_in[28];
  const int* qmask = (const int*)d_in[29];
  const int* m1 = (const int*)d_in[30];
  const int* m2 = (const int*)d_in[31];
  const int* m3 = (const int*)d_in[32];
  float* out = (float*)d_out;

  char* ws = (char*)d_ws;
  size_t off = 0;
  auto alloc_f = [&](size_t n) {
    float* ptr = (float*)(ws + off);
    off += n * 4;
    off = (off + 255) & ~(size_t)255;
    return ptr;
  };
  float* alters = alloc_f((size_t)B_ * 3 * H_);
  float* p1 = alloc_f((size_t)B_ * P_ * H_);
  float* q1 = alloc_f((size_t)B_ * Q_ * H_);
  float* pmp = alloc_f((size_t)B_ * P_ * H_);
  float* pmq = alloc_f((size_t)B_ * Q_ * H_);
  float* pasWb = alloc_f((size_t)B_ * P_ * H2_);
  float* scd = alloc_f((size_t)B_ * P_ * Q_);
  float* gi_f = alloc_f((size_t)B_ * P_ * G_);
  float* gi_b = alloc_f((size_t)B_ * P_ * G_);
  float* agg = alloc_f((size_t)B_ * P_ * H2_);
  float* sjraw = alloc_f((size_t)B_ * Q_);
  float* rqw2 = alloc_f((size_t)B_ * H_);
  float* spraw = alloc_f((size_t)B_ * P_);
  auto alloc_h = [&](size_t n) {
    _Float16* ptr = (_Float16*)(ws + off);
    off += n * 2;
    off = (off + 255) & ~(size_t)255;
    return ptr;
  };
  _Float16* wd_sw = alloc_h((size_t)16 * 8 * 64 * 4);
  _Float16* gih_sw = alloc_h((size_t)2 * 80 * 24 * 64 * 4);
  _Float16* agg_h = alloc_h((size_t)B_ * P_ * H10_);
  _Float16* whh_sw = alloc_h((size_t)2 * 4 * 24 * 64 * 8);

  k_pre<<<NB_PRE, 256, 0, stream>>>(
      alt1, alt2, alt3, m1, m2, m3, a_att_w, alters,
      Wd, wd_sw, gWih_f, gWih_b, gih_sw, gWhh_f, gWhh_b, whh_sw,
      pas, qry, Wc1, p1, Wc2, q1, Wm, pmp, pmq, Wb, pasWb, wq, vq, sjraw);
  k_scd_rq<<<B_ * Q_ * 8 + B_, 256, 0, stream>>>(
      pas, qry, wd_sw, vd, scd, sjraw, qmask, wp2, rqw2);
  k_attend<<<B_ * P_, 256, 0, stream>>>(pas, qry, p1, q1, pmp, pmq, pasWb, scd, vc, vm, qmask, agg_h);
  k_gi<<<dim3(64, 2), 256, 0, stream>>>(agg_h, gih_sw, gbih_f, gbih_b, gi_f, gi_b);
  k_gru<<<16, 512, 0, stream>>>(gi_f, gi_b, whh_sw, gbhh_f, gbhh_b, agg);
  k_spscore<<<B_ * P_, 128, 0, stream>>>(agg, wp1, rqw2, vp, spraw);
  k_final<<<B_, 256, 0, stream>>>(spraw, pmask, agg, predict_w, alters, out);
}

// Round 8
// 608.838 us; speedup vs baseline: 1.4004x; 1.2320x over previous
//
#include <hip/hip_runtime.h>

#define B_ 8
#define P_ 512
#define Q_ 64
#define A_ 16
#define H_ 128
#define H2_ 256
#define H10_ 1280
#define G_ 384

typedef float f32x4 __attribute__((ext_vector_type(4)));
typedef _Float16 half4_t __attribute__((ext_vector_type(4)));
typedef _Float16 half8_t __attribute__((ext_vector_type(8)));

__device__ __forceinline__ float fast_tanh(float x) {
  return 1.f - 2.f * __builtin_amdgcn_rcpf(1.f + __builtin_amdgcn_exp2f(2.88539008f * x));
}
__device__ __forceinline__ float fast_sigm(float x) {
  return __builtin_amdgcn_rcpf(1.f + __builtin_amdgcn_exp2f(-1.44269504f * x));
}

#define GRUBAR() asm volatile("s_waitcnt lgkmcnt(0)\n\ts_barrier" ::: "memory")

// ================= fused preprocessing mega-kernel =================
// blockIdx ranges:
//  [0,24)        alters pooling
//  [24,152)      prep_frag Wd
//  [152,2072)    prep_frag gWih_f
//  [2072,3992)   prep_frag gWih_b
//  [3992,4184)   prep_frag32 gWhh_f
//  [4184,4376)   prep_frag32 gWhh_b
//  [4376,5400)   pas -> pas_h (f16 copy)
//  [5400,5912)   Wpc = [Wc1|Wm|Wb] f16 frag pack (N=512)
//  [5912,6424)   qryT transpose
//  [6424,6680)   q-side gemm -> q1T, pmqT (transposed out)
//  [6680,6936)   qscore (2 rows/block)
#define NB_PRE 6936

__device__ __forceinline__ void prep_frag_body(int idx, const float* __restrict__ W,
                                               _Float16* __restrict__ out, int KT, int HT, int N) {
  int total = KT * HT * 64 * 4;
  if (idx >= total) return;
  int e = idx & 3;
  int l = (idx >> 2) & 63;
  int rest = idx >> 8;
  int ht = rest % HT;
  int ks = rest / HT;
  int k = ks * 16 + ((l >> 4) << 2) + e;
  int n = ht * 16 + (l & 15);
  out[idx] = (_Float16)W[(size_t)k * N + n];
}

// K=32 fragment (16x16x32 f16): k = ks*32 + (l>>4)*8 + e (self-consistent both operands)
__device__ __forceinline__ void prep_frag32_body(int idx, const float* __restrict__ W,
                                                 _Float16* __restrict__ out, int KT, int HT, int N) {
  int total = KT * HT * 64 * 8;
  if (idx >= total) return;
  int e = idx & 7;
  int l = (idx >> 3) & 63;
  int rest = idx >> 9;
  int ht = rest % HT;
  int ks = rest / HT;
  int k = ks * 32 + ((l >> 4) << 3) + e;
  int n = ht * 16 + (l & 15);
  out[idx] = (_Float16)W[(size_t)k * N + n];
}

__global__ __launch_bounds__(256) void k_pre(
    const float* __restrict__ a1, const float* __restrict__ a2, const float* __restrict__ a3,
    const int* __restrict__ m1, const int* __restrict__ m2, const int* __restrict__ m3,
    const float* __restrict__ a_att_w, float* __restrict__ alters,
    const float* __restrict__ Wd, _Float16* __restrict__ wd_sw,
    const float* __restrict__ gWih_f, const float* __restrict__ gWih_b,
    _Float16* __restrict__ gih_sw,
    const float* __restrict__ gWhh_f, const float* __restrict__ gWhh_b,
    _Float16* __restrict__ whh_sw,
    const float* __restrict__ pas, const float* __restrict__ qry,
    _Float16* __restrict__ pas_h,
    const float* __restrict__ Wc1, const float* __restrict__ Wm, const float* __restrict__ Wb,
    _Float16* __restrict__ wpc_sw,
    float* __restrict__ qryT,
    const float* __restrict__ Wc2, float* __restrict__ q1T, float* __restrict__ pmqT,
    const float* __restrict__ wq, const float* __restrict__ vq, float* __restrict__ sjraw) {
  int bx = blockIdx.x;
  int tid = threadIdx.x;
  if (bx < 24) {
    int b = bx / 3, i = bx % 3;
    const float* x = (i == 0) ? a1 : (i == 1) ? a2 : a3;
    const int* mk = (i == 0) ? m1 : (i == 1) ? m2 : m3;
    __shared__ float sc[A_];
    __shared__ float sw[A_];
    if (tid < A_) {
      const float* row = x + ((size_t)(b * A_ + tid)) * H_;
      float acc = 0.f;
      for (int h = 0; h < H_; ++h) acc += row[h] * a_att_w[h];
      sc[tid] = (mk[b * A_ + tid] != 0) ? acc : -1e30f;
    }
    __syncthreads();
    if (tid == 0) {
      float mx = -1e30f;
      for (int a = 0; a < A_; ++a) mx = fmaxf(mx, sc[a]);
      float s = 0.f;
      for (int a = 0; a < A_; ++a) { float e = __expf(sc[a] - mx); sw[a] = e; s += e; }
      float inv = 1.f / s;
      for (int a = 0; a < A_; ++a) sw[a] *= inv;
    }
    __syncthreads();
    if (tid < H_) {
      float acc = 0.f;
      for (int a = 0; a < A_; ++a) acc += sw[a] * x[((size_t)(b * A_ + a)) * H_ + tid];
      alters[((size_t)(b * 3 + i)) * H_ + tid] = acc;
    }
    return;
  }
  bx -= 24;
  if (bx < 128) { prep_frag_body(bx * 256 + tid, Wd, wd_sw, 16, 8, H_); return; }
  bx -= 128;
  if (bx < 1920) { prep_frag_body(bx * 256 + tid, gWih_f, gih_sw, 80, 24, G_); return; }
  bx -= 1920;
  if (bx < 1920) {
    prep_frag_body(bx * 256 + tid, gWih_b, gih_sw + (size_t)80 * 24 * 64 * 4, 80, 24, G_);
    return;
  }
  bx -= 1920;
  if (bx < 192) { prep_frag32_body(bx * 256 + tid, gWhh_f, whh_sw, 4, 24, G_); return; }
  bx -= 192;
  if (bx < 192) {
    prep_frag32_body(bx * 256 + tid, gWhh_b, whh_sw + (size_t)4 * 24 * 64 * 8, 4, 24, G_);
    return;
  }
  bx -= 192;
  if (bx < 1024) {
    // pas -> f16, 4 elems/thread
    int idx = bx * 256 + tid;
    float4 v = *(const float4*)(pas + (size_t)idx * 4);
    half4_t h;
    h[0] = (_Float16)v.x; h[1] = (_Float16)v.y; h[2] = (_Float16)v.z; h[3] = (_Float16)v.w;
    *(half4_t*)(pas_h + (size_t)idx * 4) = h;
    return;
  }
  bx -= 1024;
  if (bx < 512) {
    // Wpc fragment pack: combined cols [Wc1 | Wm | Wb], N=512, KT=16, HT=32
    int idx = bx * 256 + tid;
    int e = idx & 3;
    int l = (idx >> 2) & 63;
    int rest = idx >> 8;
    int ht = rest & 31;
    int ks = rest >> 5;
    int k = ks * 16 + ((l >> 4) << 2) + e;
    int n = ht * 16 + (l & 15);
    float v = (n < 128) ? Wc1[(size_t)k * 128 + n]
            : (n < 256) ? Wm[(size_t)k * 128 + (n - 128)]
                        : Wb[(size_t)k * 256 + (n - 256)];
    wpc_sw[idx] = (_Float16)v;
    return;
  }
  bx -= 512;
  if (bx < 512) {
    // qryT[b][d][q] = qry[b][q][d]
    int idx = bx * 256 + tid;
    int q = idx & 63;
    int d = (idx >> 6) & 255;
    int b = idx >> 14;
    qryT[idx] = qry[((size_t)(b * Q_ + q)) * H2_ + d];
    return;
  }
  bx -= 512;
  if (bx < 256) {
    // q-side gemm, transposed outputs: q1T/pmqT[b][h][q]
    int idx = bx * 256 + tid;
    int h = idx & 127;
    int rest = idx >> 7;
    int q = rest & 63;
    int b = rest >> 6;
    const float* qr = qry + ((size_t)(b * Q_ + q)) * H2_;
    float a1v = 0.f, a2v = 0.f;
#pragma unroll 4
    for (int d = 0; d < H2_; ++d) {
      float qv = qr[d];
      a1v += qv * Wc2[(size_t)d * H_ + h];
      a2v += qv * Wm[(size_t)d * H_ + h];
    }
    q1T[((size_t)(b * H_ + h)) * Q_ + q] = a1v;
    pmqT[((size_t)(b * H_ + h)) * Q_ + q] = a2v;
    return;
  }
  bx -= 256;
  {
    // qscore: 2 rows/block
    int rs = tid >> 7;
    int h = tid & 127;
    int row = bx * 2 + rs;
    const float* qr = qry + (size_t)row * H2_;
    float acc = 0.f;
#pragma unroll 4
    for (int d = 0; d < H2_; ++d) acc += qr[d] * wq[(size_t)d * H_ + h];
    float v = fast_tanh(acc) * vq[h];
    for (int m = 32; m >= 1; m >>= 1) v += __shfl_xor(v, m);
    __shared__ float par[2][2];
    if ((h & 63) == 0) par[rs][h >> 6] = v;
    __syncthreads();
    if (h == 0) sjraw[row] = par[rs][0] + par[rs][1];
  }
}

// ================= sc_d (MFMA) + rq + pas-side MFMA gemm, one launch =================
// blocks: [0,4096) scd; [4096,4104) rq; [4104,4232) pas@[Wc1|Wm|Wb] -> p1,pmp,pasWb
__global__ __launch_bounds__(256) void k_scd_rq(
    const float* __restrict__ pas, const float* __restrict__ qry,
    const _Float16* __restrict__ wd_sw, const float* __restrict__ vd,
    float* __restrict__ scd,
    const float* __restrict__ sjraw, const int* __restrict__ qmask,
    const float* __restrict__ wp2, float* __restrict__ rqw2,
    const _Float16* __restrict__ pas_h, const _Float16* __restrict__ wpc_sw,
    float* __restrict__ p1, float* __restrict__ pmp, float* __restrict__ pasWb) {
  int bx0 = blockIdx.x;
  int tid = threadIdx.x;
  if (bx0 < B_ * Q_ * 8) {
    int pt = bx0 & 7;
    int rem = bx0 >> 3;
    int q = rem & (Q_ - 1);
    int b = rem >> 6;
    int w = tid >> 6, l = tid & 63;
    __shared__ __align__(16) float qs[H2_];
    __shared__ float vds[H_];
    if (tid < H2_) qs[tid] = qry[((size_t)(b * Q_ + q)) * H2_ + tid];
    if (tid < H_) vds[tid] = vd[tid];
    __syncthreads();
    int arow = pt * 64 + w * 16 + (l & 15);
    const float* prow = pas + ((size_t)(b * P_) + arow) * H2_;
    int ko = (l >> 4) << 2;
    f32x4 acc[8] = {};
#pragma unroll
    for (int ks = 0; ks < 16; ++ks) {
      int j0 = ks * 16 + ko;
      float4 pa = *(const float4*)(prow + j0);
      float4 qa = *(const float4*)(qs + j0);
      half4_t a;
      a[0] = (_Float16)(pa.x * qa.x);
      a[1] = (_Float16)(pa.y * qa.y);
      a[2] = (_Float16)(pa.z * qa.z);
      a[3] = (_Float16)(pa.w * qa.w);
      const _Float16* bb = wd_sw + (((size_t)(ks * 8) * 64) + l) * 4;
#pragma unroll
      for (int ht = 0; ht < 8; ++ht) {
        half4_t bf = *(const half4_t*)(bb + (size_t)ht * 64 * 4);
        acc[ht] = __builtin_amdgcn_mfma_f32_16x16x16f16(a, bf, acc[ht], 0, 0, 0);
      }
    }
    float part[4] = {0.f, 0.f, 0.f, 0.f};
#pragma unroll
    for (int ht = 0; ht < 8; ++ht) {
      float v = vds[ht * 16 + (l & 15)];
#pragma unroll
      for (int j = 0; j < 4; ++j) part[j] += v * fast_tanh(acc[ht][j]);
    }
#pragma unroll
    for (int j = 0; j < 4; ++j) {
      float s = part[j];
      s += __shfl_xor(s, 1);
      s += __shfl_xor(s, 2);
      s += __shfl_xor(s, 4);
      s += __shfl_xor(s, 8);
      part[j] = s;
    }
    if ((l & 15) == 0) {
      int pr = pt * 64 + w * 16 + ((l >> 4) << 2);
#pragma unroll
      for (int j = 0; j < 4; ++j)
        scd[((size_t)b * P_ + pr + j) * Q_ + q] = part[j];
    }
    return;
  }
  if (bx0 < B_ * Q_ * 8 + B_) {
    // rq + rq@wp2
    int b = bx0 - B_ * Q_ * 8;
    int t = tid;
    __shared__ float sj[Q_];
    __shared__ float rql[H2_];
    if (t < Q_) {
      float s = (qmask[b * Q_ + t] != 0) ? sjraw[b * Q_ + t] : -1e30f;
      float mx = s;
      for (int m = 32; m >= 1; m >>= 1) mx = fmaxf(mx, __shfl_xor(mx, m));
      float e = __expf(s - mx);
      float sum = e;
      for (int m = 32; m >= 1; m >>= 1) sum += __shfl_xor(sum, m);
      sj[t] = e / sum;
    }
    __syncthreads();
    {
      float acc = 0.f;
      const float* qcol = qry + (size_t)b * Q_ * H2_ + t;
#pragma unroll 8
      for (int q = 0; q < Q_; ++q) acc += sj[q] * qcol[(size_t)q * H2_];
      rql[t] = acc;
    }
    __syncthreads();
    if (t < H_) {
      float acc = 0.f;
#pragma unroll 4
      for (int d = 0; d < H2_; ++d) acc += rql[d] * wp2[(size_t)d * H_ + t];
      rqw2[b * H_ + t] = acc;
    }
    return;
  }
  {
    // pas-side MFMA gemm: 128 blocks = 64 row-tiles x 2 N-halves
    int bx2 = bx0 - (B_ * Q_ * 8 + B_);
    int rt = bx2 >> 1, nh = bx2 & 1;
    int w = tid >> 6, l = tid & 63;
    int p0 = rt * 64 + w * 16;
    const _Float16* arow = pas_h + ((size_t)(p0 + (l & 15))) * H2_ + ((l >> 4) << 2);
    const _Float16* bbase = wpc_sw + (size_t)l * 4;
    f32x4 acc[16] = {};
    for (int ks = 0; ks < 16; ++ks) {
      half4_t a = *(const half4_t*)(arow + ks * 16);
      const _Float16* bkt = bbase + ((size_t)(ks * 32 + nh * 16)) * 64 * 4;
#pragma unroll
      for (int ht = 0; ht < 16; ++ht) {
        half4_t bf = *(const half4_t*)(bkt + (size_t)ht * 64 * 4);
        acc[ht] = __builtin_amdgcn_mfma_f32_16x16x16f16(a, bf, acc[ht], 0, 0, 0);
      }
    }
    int r0 = p0 + ((l >> 4) << 2);
#pragma unroll
    for (int ht = 0; ht < 16; ++ht) {
      int col = (nh * 16 + ht) * 16 + (l & 15);
#pragma unroll
      for (int j = 0; j < 4; ++j) {
        float v = acc[ht][j];
        size_t row = r0 + j;
        if (col < 128) p1[row * H_ + col] = v;
        else if (col < 256) pmp[row * H_ + (col - 128)] = v;
        else pasWb[row * H2_ + (col - 256)] = v;
      }
    }
  }
}

// ---------------- k_attend v2: coalesced score phase via transposed q-side ----------------
__global__ __launch_bounds__(256) void k_attend(
    const float* __restrict__ pas, const float* __restrict__ qry,
    const float* __restrict__ p1, const float* __restrict__ pmp,
    const float* __restrict__ q1T, const float* __restrict__ pmqT,
    const float* __restrict__ qryT,
    const float* __restrict__ pasWb, const float* __restrict__ scd,
    const float* __restrict__ vc, const float* __restrict__ vm,
    const int* __restrict__ qmask, _Float16* __restrict__ agg_h) {
  int bx = blockIdx.x;
  int b = bx >> 9, p = bx & (P_ - 1);
  int tid = threadIdx.x;
  __shared__ float p1s[H_], pmps[H_];
  __shared__ float pbs[H2_];
  __shared__ float sscd[Q_];
  __shared__ float ps[3][4][Q_];
  __shared__ float asw[4][Q_];
  size_t rowp = (size_t)b * P_ + p;
  if (tid < H_) {
    p1s[tid] = p1[rowp * H_ + tid];
    pmps[tid] = pmp[rowp * H_ + tid];
  }
  if (tid < H2_) pbs[tid] = pasWb[rowp * H2_ + tid];
  if (tid < Q_) sscd[tid] = scd[rowp * Q_ + tid];
  __syncthreads();
  {
    int q = tid & 63, part = tid >> 6;
    const float* q1b = q1T + (size_t)b * H_ * Q_;
    const float* pmqb = pmqT + (size_t)b * H_ * Q_;
    const float* qTb = qryT + (size_t)b * H2_ * Q_;
    float s_c = 0.f, s_m = 0.f, s_b = 0.f;
    int h0 = part * 32;
#pragma unroll 4
    for (int i = 0; i < 32; ++i) {
      int h = h0 + i;
      s_c += fast_tanh(p1s[h] + q1b[h * Q_ + q]) * vc[h];
      s_m += fast_tanh(pmqb[h * Q_ + q] - pmps[h]) * vm[h];
    }
    int d0 = part * 64;
#pragma unroll 4
    for (int i = 0; i < 64; ++i) {
      int d = d0 + i;
      s_b += pbs[d] * qTb[d * Q_ + q];
    }
    ps[0][part][q] = s_c;
    ps[1][part][q] = s_b;
    ps[2][part][q] = s_m;
  }
  __syncthreads();
  {
    int wv = tid >> 6, lane = tid & 63;
    float s;
    if (wv == 2) s = sscd[lane];
    else {
      int arr = (wv == 3) ? 2 : wv;
      s = (ps[arr][0][lane] + ps[arr][1][lane]) + (ps[arr][2][lane] + ps[arr][3][lane]);
    }
    s = (qmask[b * Q_ + lane] != 0) ? s : -1e30f;
    float mx = s;
    for (int m = 32; m >= 1; m >>= 1) mx = fmaxf(mx, __shfl_xor(mx, m));
    float e = __expf(s - mx);
    float sum = e;
    for (int m = 32; m >= 1; m >>= 1) sum += __shfl_xor(sum, m);
    asw[wv][lane] = e / sum;
  }
  __syncthreads();
  {
    int d = tid;
    const float* qcol = qry + (size_t)b * Q_ * H2_ + d;
    float o0 = 0.f, o1 = 0.f, o2 = 0.f, o3 = 0.f;
#pragma unroll 8
    for (int q2 = 0; q2 < Q_; ++q2) {
      float qv = qcol[(size_t)q2 * H2_];
      o0 += asw[0][q2] * qv;
      o1 += asw[1][q2] * qv;
      o2 += asw[2][q2] * qv;
      o3 += asw[3][q2] * qv;
    }
    _Float16* arow = agg_h + rowp * H10_;
    arow[d] = (_Float16)pas[rowp * H2_ + d];
    arow[256 + d] = (_Float16)o0;
    arow[512 + d] = (_Float16)o1;
    arow[768 + d] = (_Float16)o2;
    arow[1024 + d] = (_Float16)o3;
  }
}

// ---------------- gi = agg_in @ gWih + gbih (both dirs), f16 MFMA ----------------
__global__ __launch_bounds__(256) void k_gi(
    const _Float16* __restrict__ agg_h, const _Float16* __restrict__ gih_sw,
    const float* __restrict__ gbih_f, const float* __restrict__ gbih_b,
    float* __restrict__ gi_f, float* __restrict__ gi_b) {
  int dir = blockIdx.y;
  const float* gbih = dir ? gbih_b : gbih_f;
  float* gi = dir ? gi_b : gi_f;
  int tid = threadIdx.x;
  int w = tid >> 6, l = tid & 63;
  int p0 = blockIdx.x * 64 + w * 16;
  const _Float16* arow = agg_h + ((size_t)(p0 + (l & 15))) * H10_ + ((l >> 4) << 2);
  const _Float16* bbase = gih_sw + (size_t)dir * 80 * 24 * 64 * 4 + (size_t)l * 4;
  f32x4 acc[24] = {};
  for (int ks = 0; ks < 80; ++ks) {
    half4_t a = *(const half4_t*)(arow + ks * 16);
    const _Float16* bkt = bbase + (size_t)ks * 24 * 64 * 4;
#pragma unroll
    for (int ht = 0; ht < 24; ++ht) {
      half4_t bf = *(const half4_t*)(bkt + (size_t)ht * 64 * 4);
      acc[ht] = __builtin_amdgcn_mfma_f32_16x16x16f16(a, bf, acc[ht], 0, 0, 0);
    }
  }
  int r0 = p0 + ((l >> 4) << 2);
#pragma unroll
  for (int ht = 0; ht < 24; ++ht) {
    int col = ht * 16 + (l & 15);
    float bias = gbih[col];
#pragma unroll
    for (int j = 0; j < 4; ++j)
      gi[((size_t)(r0 + j)) * G_ + col] = acc[ht][j] + bias;
  }
}

// ---------------- GRU scan v7: K=32 MFMA, 6 independent 2-deep chains ----------------
__global__ __attribute__((amdgpu_waves_per_eu(2, 2))) __launch_bounds__(512) void k_gru(
    const float* __restrict__ gi_f, const float* __restrict__ gi_b,
    const _Float16* __restrict__ whh_sw,
    const float* __restrict__ bhh_f, const float* __restrict__ bhh_b,
    float* __restrict__ agg) {
  int dir = blockIdx.x >> 3;
  int bb = blockIdx.x & 7;
  const float* gi = dir ? gi_b : gi_f;
  const float* bhh = dir ? bhh_b : bhh_f;
  int tid = threadIdx.x;
  int w = tid >> 6, l = tid & 63;
  int j = w * 16 + (l & 15);
  half8_t Bf[3][4];
  {
    const _Float16* wb = whh_sw + (size_t)dir * 4 * 24 * 64 * 8;
#pragma unroll
    for (int g = 0; g < 3; ++g) {
      int ct = g * 8 + w;
#pragma unroll
      for (int ks = 0; ks < 4; ++ks)
        Bf[g][ks] = *(const half8_t*)(wb + (((size_t)(ks * 24 + ct)) * 64 + l) * 8);
    }
  }
  float bhr = bhh[j], bhz = bhh[128 + j], bhn = bhh[256 + j];
  __shared__ __align__(16) _Float16 hsbuf[2][H_];
  if (tid < H_) hsbuf[0][tid] = (_Float16)0.f;
  float hprev = 0.f;
  int p = dir ? (P_ - 1) : 0;
  int dp = dir ? -1 : 1;
  size_t gbase = (size_t)bb * P_;
  float g0r, g0z, g0n, g1r, g1z, g1n;
  {
    size_t r0 = (gbase + p) * G_;
    g0r = gi[r0 + j]; g0z = gi[r0 + 128 + j]; g0n = gi[r0 + 256 + j];
    size_t r1 = (gbase + p + dp) * G_;
    g1r = gi[r1 + j]; g1z = gi[r1 + 128 + j]; g1n = gi[r1 + 256 + j];
  }
  GRUBAR();
  int cur = 0;
  int ao = (l >> 4) << 3;
  for (int t = 0; t < P_; ++t) {
    float g2r = 0.f, g2z = 0.f, g2n = 0.f;
    if (t + 2 < P_) {
      size_t r2 = (gbase + p + 2 * dp) * G_;
      g2r = gi[r2 + j]; g2z = gi[r2 + 128 + j]; g2n = gi[r2 + 256 + j];
    }
    const _Float16* hb = hsbuf[cur];
    half8_t ha[4];
#pragma unroll
    for (int ks = 0; ks < 4; ++ks) ha[ks] = *(const half8_t*)(hb + ks * 32 + ao);
    f32x4 arL = {}, arH = {}, azL = {}, azH = {}, anL = {}, anH = {};
    arL = __builtin_amdgcn_mfma_f32_16x16x32_f16(ha[0], Bf[0][0], arL, 0, 0, 0);
    azL = __builtin_amdgcn_mfma_f32_16x16x32_f16(ha[0], Bf[1][0], azL, 0, 0, 0);
    anL = __builtin_amdgcn_mfma_f32_16x16x32_f16(ha[0], Bf[2][0], anL, 0, 0, 0);
    arH = __builtin_amdgcn_mfma_f32_16x16x32_f16(ha[2], Bf[0][2], arH, 0, 0, 0);
    azH = __builtin_amdgcn_mfma_f32_16x16x32_f16(ha[2], Bf[1][2], azH, 0, 0, 0);
    anH = __builtin_amdgcn_mfma_f32_16x16x32_f16(ha[2], Bf[2][2], anH, 0, 0, 0);
    arL = __builtin_amdgcn_mfma_f32_16x16x32_f16(ha[1], Bf[0][1], arL, 0, 0, 0);
    azL = __builtin_amdgcn_mfma_f32_16x16x32_f16(ha[1], Bf[1][1], azL, 0, 0, 0);
    anL = __builtin_amdgcn_mfma_f32_16x16x32_f16(ha[1], Bf[2][1], anL, 0, 0, 0);
    arH = __builtin_amdgcn_mfma_f32_16x16x32_f16(ha[3], Bf[0][3], arH, 0, 0, 0);
    azH = __builtin_amdgcn_mfma_f32_16x16x32_f16(ha[3], Bf[1][3], azH, 0, 0, 0);
    anH = __builtin_amdgcn_mfma_f32_16x16x32_f16(ha[3], Bf[2][3], anH, 0, 0, 0);
    float arS = arL[0] + arH[0];
    float azS = azL[0] + azH[0];
    float anS = anL[0] + anH[0];
    float r = fast_sigm(g0r + arS + bhr);
    float z = fast_sigm(g0z + azS + bhz);
    float nn = fast_tanh(g0n + r * (anS + bhn));
    float hnew = (1.f - z) * nn + z * hprev;
    hprev = hnew;
    if (l < 16) {
      hsbuf[cur ^ 1][j] = (_Float16)hnew;
      agg[(size_t)(gbase + p) * H2_ + dir * H_ + j] = hnew;
    }
    GRUBAR();
    cur ^= 1;
    g0r = g1r; g0z = g1z; g0n = g1n;
    g1r = g2r; g1z = g2z; g1n = g2n;
    p += dp;
  }
}

// ---------------- sp raw scores ----------------
__global__ __launch_bounds__(128) void k_spscore(
    const float* __restrict__ agg, const float* __restrict__ wp1,
    const float* __restrict__ rqw2, const float* __restrict__ vp,
    float* __restrict__ spraw) {
  int bx = blockIdx.x;
  int b = bx >> 9, p = bx & (P_ - 1);
  int h = threadIdx.x;
  const float* ar = agg + ((size_t)b * P_ + p) * H2_;
  float acc = rqw2[b * H_ + h];
#pragma unroll 8
  for (int d = 0; d < H2_; ++d) acc += ar[d] * wp1[(size_t)d * H_ + h];
  float v = fast_tanh(acc) * vp[h];
  for (int m = 32; m >= 1; m >>= 1) v += __shfl_xor(v, m);
  __shared__ float par[2];
  if ((h & 63) == 0) par[h >> 6] = v;
  __syncthreads();
  if (h == 0) spraw[bx] = par[0] + par[1];
}

// ---------------- final head ----------------
__global__ __launch_bounds__(256) void k_final(
    const float* __restrict__ spraw, const int* __restrict__ pmask,
    const float* __restrict__ agg, const float* __restrict__ predict_w,
    const float* __restrict__ alters, float* __restrict__ out) {
  int b = blockIdx.x;
  int t = threadIdx.x;
  __shared__ float sp[P_];
  __shared__ float red[4];
  __shared__ float rpr[H2_];
  __shared__ float rpl[H_];
  __shared__ float lg[3];
  float s0 = (pmask[b * P_ + t] != 0) ? spraw[b * P_ + t] : -1e30f;
  float s1 = (pmask[b * P_ + 256 + t] != 0) ? spraw[b * P_ + 256 + t] : -1e30f;
  float mx = fmaxf(s0, s1);
  for (int m = 32; m >= 1; m >>= 1) mx = fmaxf(mx, __shfl_xor(mx, m));
  if ((t & 63) == 0) red[t >> 6] = mx;
  __syncthreads();
  mx = fmaxf(fmaxf(red[0], red[1]), fmaxf(red[2], red[3]));
  float e0 = __expf(s0 - mx), e1 = __expf(s1 - mx);
  float ss = e0 + e1;
  for (int m = 32; m >= 1; m >>= 1) ss += __shfl_xor(ss, m);
  __syncthreads();
  if ((t & 63) == 0) red[t >> 6] = ss;
  __syncthreads();
  float tot = red[0] + red[1] + red[2] + red[3];
  float inv = 1.f / tot;
  sp[t] = e0 * inv;
  sp[256 + t] = e1 * inv;
  __syncthreads();
  {
    float acc = 0.f;
    const float* acol = agg + (size_t)b * P_ * H2_ + t;
#pragma unroll 8
    for (int p = 0; p < P_; ++p) acc += sp[p] * acol[(size_t)p * H2_];
    rpr[t] = acc;
  }
  __syncthreads();
  if (t < H_) {
    float acc = 0.f;
#pragma unroll 4
    for (int d = 0; d < H2_; ++d) acc += rpr[d] * predict_w[(size_t)d * H_ + t];
    rpl[t] = (acc > 0.f) ? acc : 0.01f * acc;
  }
  __syncthreads();
  if (t < 3) {
    float acc = 0.f;
    const float* al = alters + ((size_t)(b * 3 + t)) * H_;
    for (int h = 0; h < H_; ++h) acc += al[h] * rpl[h];
    lg[t] = acc;
  }
  __syncthreads();
  if (t == 0) {
    float m3 = fmaxf(lg[0], fmaxf(lg[1], lg[2]));
    float x0 = __expf(lg[0] - m3), x1 = __expf(lg[1] - m3), x2 = __expf(lg[2] - m3);
    float is = 1.f / (x0 + x1 + x2);
    out[b * 3 + 0] = x0 * is;
    out[b * 3 + 1] = x1 * is;
    out[b * 3 + 2] = x2 * is;
  }
}

extern "C" void kernel_launch(void* const* d_in, const int* in_sizes, int n_in,
                              void* d_out, int out_size, void* d_ws, size_t ws_size,
                              hipStream_t stream) {
  (void)in_sizes; (void)n_in; (void)out_size; (void)ws_size;
  const float* pas = (const float*)d_in[0];
  const float* qry = (const float*)d_in[1];
  const float* alt1 = (const float*)d_in[2];
  const float* alt2 = (const float*)d_in[3];
  const float* alt3 = (const float*)d_in[4];
  const float* a_att_w = (const float*)d_in[5];
  const float* Wc1 = (const float*)d_in[6];
  const float* Wc2 = (const float*)d_in[7];
  const float* vc = (const float*)d_in[8];
  const float* Wb = (const float*)d_in[9];
  const float* Wd = (const float*)d_in[10];
  const float* vd = (const float*)d_in[11];
  const float* Wm = (const float*)d_in[12];
  const float* vm = (const float*)d_in[13];
  const float* wq = (const float*)d_in[14];
  const float* vq = (const float*)d_in[15];
  const float* wp1 = (const float*)d_in[16];
  const float* wp2 = (const float*)d_in[17];
  const float* vp = (const float*)d_in[18];
  const float* predict_w = (const float*)d_in[19];
  const float* gWih_f = (const float*)d_in[20];
  const float* gWhh_f = (const float*)d_in[21];
  const float* gbih_f = (const float*)d_in[22];
  const float* gbhh_f = (const float*)d_in[23];
  const float* gWih_b = (const float*)d_in[24];
  const float* gWhh_b = (const float*)d_in[25];
  const float* gbih_b = (const float*)d_in[26];
  const float* gbhh_b = (const float*)d_in[27];
  const int* pmask = (const int*)d_in[28];
  const int* qmask = (const int*)d_in[29];
  const int* m1 = (const int*)d_in[30];
  const int* m2 = (const int*)d_in[31];
  const int* m3 = (const int*)d_in[32];
  float* out = (float*)d_out;

  char* ws = (char*)d_ws;
  size_t off = 0;
  auto alloc_f = [&](size_t n) {
    float* ptr = (float*)(ws + off);
    off += n * 4;
    off = (off + 255) & ~(size_t)255;
    return ptr;
  };
  float* alters = alloc_f((size_t)B_ * 3 * H_);
  float* p1 = alloc_f((size_t)B_ * P_ * H_);
  float* pmp = alloc_f((size_t)B_ * P_ * H_);
  float* pasWb = alloc_f((size_t)B_ * P_ * H2_);
  float* scd = alloc_f((size_t)B_ * P_ * Q_);
  float* gi_f = alloc_f((size_t)B_ * P_ * G_);
  float* gi_b = alloc_f((size_t)B_ * P_ * G_);
  float* agg = alloc_f((size_t)B_ * P_ * H2_);
  float* sjraw = alloc_f((size_t)B_ * Q_);
  float* rqw2 = alloc_f((size_t)B_ * H_);
  float* spraw = alloc_f((size_t)B_ * P_);
  float* q1T = alloc_f((size_t)B_ * H_ * Q_);
  float* pmqT = alloc_f((size_t)B_ * H_ * Q_);
  float* qryT = alloc_f((size_t)B_ * H2_ * Q_);
  auto alloc_h = [&](size_t n) {
    _Float16* ptr = (_Float16*)(ws + off);
    off += n * 2;
    off = (off + 255) & ~(size_t)255;
    return ptr;
  };
  _Float16* wd_sw = alloc_h((size_t)16 * 8 * 64 * 4);
  _Float16* gih_sw = alloc_h((size_t)2 * 80 * 24 * 64 * 4);
  _Float16* agg_h = alloc_h((size_t)B_ * P_ * H10_);
  _Float16* whh_sw = alloc_h((size_t)2 * 4 * 24 * 64 * 8);
  _Float16* pas_h = alloc_h((size_t)B_ * P_ * H2_);
  _Float16* wpc_sw = alloc_h((size_t)16 * 32 * 64 * 4);

  k_pre<<<NB_PRE, 256, 0, stream>>>(
      alt1, alt2, alt3, m1, m2, m3, a_att_w, alters,
      Wd, wd_sw, gWih_f, gWih_b, gih_sw, gWhh_f, gWhh_b, whh_sw,
      pas, qry, pas_h, Wc1, Wm, Wb, wpc_sw, qryT, Wc2, q1T, pmqT, wq, vq, sjraw);
  k_scd_rq<<<B_ * Q_ * 8 + B_ + 128, 256, 0, stream>>>(
      pas, qry, wd_sw, vd, scd, sjraw, qmask, wp2, rqw2,
      pas_h, wpc_sw, p1, pmp, pasWb);
  k_attend<<<B_ * P_, 256, 0, stream>>>(
      pas, qry, p1, pmp, q1T, pmqT, qryT, pasWb, scd, vc, vm, qmask, agg_h);
  k_gi<<<dim3(64, 2), 256, 0, stream>>>(agg_h, gih_sw, gbih_f, gbih_b, gi_f, gi_b);
  k_gru<<<16, 512, 0, stream>>>(gi_f, gi_b, whh_sw, gbhh_f, gbhh_b, agg);
  k_spscore<<<B_ * P_, 128, 0, stream>>>(agg, wp1, rqw2, vp, spraw);
  k_final<<<B_, 256, 0, stream>>>(spraw, pmask, agg, predict_w, alters, out);
}